// Round 1
// baseline (981.157 us; speedup 1.0000x reference)
//
#include <hip/hip_runtime.h>

#define NFREQ 2049
#define L1LEN 1025
#define L2LEN 513

// ---------------- workspace layout (float offsets) ----------------
#define OFF_FFT     0ull                 // 128 * 4098 = 524544
#define OFF_POOLED  524544ull            // 8192
#define OFF_TW      532736ull            // 256
#define OFF_TI      532992ull            // 256 (ints)
#define OFF_SRWLOG  533248ull            // 16
#define OFF_W2T     533264ull            // 10240
#define OFF_EW2T    543504ull            // 327680
#define OFF_EW3T    871184ull            // 393216
#define OFF_E1      1264400ull           // 8396800
#define OFF_E2      9661200ull           // 8404992
#define OFF_FINAL   18066192ull          // 8404992
// total ~ 26.5M floats ~ 101 MiB

__device__ __forceinline__ float relu_f(float x) { return fmaxf(x, 0.0f); }

// ---------------- init: zero accumulators + transpose weights ----------------
__global__ void init_kernel(float* POOLED, float* SRWLOG, float* W2T, float* EW2T, float* EW3T,
                            const float* g_w2, const float* ew2, const float* ew3) {
    int tid = blockIdx.x * blockDim.x + threadIdx.x;
    int stride = gridDim.x * blockDim.x;
    for (int i = tid; i < 8192 + 16; i += stride) {
        if (i < 8192) POOLED[i] = 0.0f; else SRWLOG[i - 8192] = 0.0f;
    }
    // g_w2 (64,32,5) -> W2T[(c*5+t)*64 + o]
    for (int i = tid; i < 10240; i += stride) {
        int ct = i >> 6, o = i & 63;
        W2T[i] = g_w2[o * 160 + ct];
    }
    // ew2 (8,128,64,5) -> EW2T[e*40960 + (c*5+t)*128 + o]
    for (int i = tid; i < 327680; i += stride) {
        int e = i / 40960, r = i % 40960;
        int ct = r >> 7, o = r & 127;
        EW2T[i] = ew2[(e * 128 + o) * 320 + ct];
    }
    // ew3 (8,128,128,3) -> EW3T[e*49152 + (c*3+t)*128 + o]
    for (int i = tid; i < 393216; i += stride) {
        int e = i / 49152, r = i % 49152;
        int ct = r >> 7, o = r & 127;
        EW3T[i] = ew3[(e * 128 + o) * 384 + ct];
    }
}

// ---------------- windowed rfft(4096) via 2048-pt complex FFT ----------------
__global__ __launch_bounds__(256) void fft_kernel(const float* __restrict__ x, float* __restrict__ FFT) {
    __shared__ float re[2048];
    __shared__ float im[2048];
    const float PI = 3.14159265358979323846f;
    int b = blockIdx.x, t = threadIdx.x;
    const float* xb = x + b * 4096;
    const float wstep = 2.0f * PI / 4096.0f;
    for (int i = t; i < 2048; i += 256) {
        int j = (int)(__brev((unsigned)i) >> 21);   // 11-bit reversal
        float w0 = 0.5f * (1.0f - cosf(wstep * (float)(2 * j)));
        float w1 = 0.5f * (1.0f - cosf(wstep * (float)(2 * j + 1)));
        re[i] = xb[2 * j] * w0;
        im[i] = xb[2 * j + 1] * w1;
    }
    // 11 radix-2 DIT stages
    for (int s = 1; s <= 11; ++s) {
        __syncthreads();
        int half = 1 << (s - 1);
        for (int bf = t; bf < 1024; bf += 256) {
            int grp = bf >> (s - 1);
            int pos = bf & (half - 1);
            int i1 = (grp << s) + pos;
            int i2 = i1 + half;
            float ang = -PI * (float)pos / (float)half;  // -2*pi*pos/m
            float wr = cosf(ang), wi = sinf(ang);
            float ar = re[i2], ai = im[i2];
            float tr = wr * ar - wi * ai;
            float ti = wr * ai + wi * ar;
            float br = re[i1], bi = im[i1];
            re[i2] = br - tr; im[i2] = bi - ti;
            re[i1] = br + tr; im[i1] = bi + ti;
        }
    }
    __syncthreads();
    // real-input post-process, ortho scale 1/64
    const float scale = 1.0f / 64.0f;
    for (int k = t; k <= 2048; k += 256) {
        int k1 = k & 2047;
        int k2 = (2048 - k) & 2047;
        float zr = re[k1], zi = im[k1];
        float yr = re[k2], yi = im[k2];
        float Er = 0.5f * (zr + yr), Ei = 0.5f * (zi - yi);
        float Or = 0.5f * (zi + yi), Oi = 0.5f * (yr - zr);
        float th = PI * (float)k / 2048.0f;
        float c2 = cosf(th), s3 = sinf(th);
        float Xr = (Er + c2 * Or + s3 * Oi) * scale;
        float Xi = (Ei + c2 * Oi - s3 * Or) * scale;
        FFT[b * 4098 + k] = Xr;
        FFT[b * 4098 + 2049 + k] = Xi;
    }
}

// ---------------- gate: fused conv1 + conv2 + mean-pool ----------------
// grid (33, 128), block 256 = 64 positions x 4 o-groups (16 o each)
__global__ __launch_bounds__(256) void gate_kernel(const float* __restrict__ FFT,
                                                   const float* __restrict__ g_w1, const float* __restrict__ g_b1,
                                                   const float* __restrict__ W2T, const float* __restrict__ g_b2,
                                                   float* __restrict__ POOLED) {
    __shared__ float fS[2][72];
    __shared__ float hS[32][68];
    int b = blockIdx.y;
    int p0 = blockIdx.x * 64;
    int t = threadIdx.x;
    for (int i = t; i < 144; i += 256) {
        int ch = i / 72, r = i % 72;
        int pos = p0 - 4 + r;
        fS[ch][r] = (pos >= 0 && pos < NFREQ) ? FFT[b * 4098 + ch * NFREQ + pos] : 0.0f;
    }
    __syncthreads();
    for (int i = t; i < 32 * 68; i += 256) {
        int c1 = i / 68, r = i % 68;
        int pos = p0 - 2 + r;
        float v = 0.0f;
        if (pos >= 0 && pos < NFREQ) {
            float a = g_b1[c1];
            #pragma unroll
            for (int cc = 0; cc < 2; ++cc)
                #pragma unroll
                for (int tt = 0; tt < 5; ++tt)
                    a = fmaf(fS[cc][r + tt], g_w1[(c1 * 2 + cc) * 5 + tt], a);
            v = relu_f(a);
        }
        hS[c1][r] = v;
    }
    __syncthreads();
    int lq = t & 63;
    int q = p0 + lq;
    int og = __builtin_amdgcn_readfirstlane(t >> 6);  // wave-uniform o-group
    float acc[16];
    #pragma unroll
    for (int i = 0; i < 16; ++i) acc[i] = 0.0f;
    for (int c = 0; c < 32; ++c) {
        #pragma unroll
        for (int tt = 0; tt < 5; ++tt) {
            float xv = hS[c][lq + tt];
            const float* wr = W2T + (c * 5 + tt) * 64 + og * 16;
            #pragma unroll
            for (int o = 0; o < 16; ++o) acc[o] = fmaf(wr[o], xv, acc[o]);
        }
    }
    bool valid = (q < NFREQ);
    #pragma unroll
    for (int o = 0; o < 16; ++o) {
        float v = valid ? relu_f(acc[o] + g_b2[og * 16 + o]) : 0.0f;
        #pragma unroll
        for (int m = 32; m >= 1; m >>= 1) v += __shfl_xor(v, m, 64);
        if (lq == 0) atomicAdd(&POOLED[b * 64 + og * 16 + o], v);
    }
}

// ---------------- router MLP + softmax + top2 + aux partials ----------------
__global__ __launch_bounds__(128) void mlp_kernel(const float* __restrict__ POOLED,
                                                  const float* __restrict__ m_w1, const float* __restrict__ m_b1,
                                                  const float* __restrict__ m_w2, const float* __restrict__ m_b2,
                                                  float* TW, int* TI, float* SRWLOG) {
    __shared__ float hid[128];
    __shared__ float lgS[8];
    __shared__ float rwS[8];
    int b = blockIdx.x, t = threadIdx.x;
    const float inv = 1.0f / 2049.0f;
    {
        float h = m_b1[t];
        for (int c = 0; c < 64; ++c)
            h = fmaf(POOLED[b * 64 + c] * inv, m_w1[t * 64 + c], h);
        hid[t] = relu_f(h);
    }
    __syncthreads();
    if (t < 8) {
        float lg = m_b2[t];
        for (int j = 0; j < 128; ++j) lg = fmaf(hid[j], m_w2[t * 128 + j], lg);
        lgS[t] = lg;
    }
    __syncthreads();
    if (t == 0) {
        float mx = lgS[0];
        for (int e = 1; e < 8; ++e) mx = fmaxf(mx, lgS[e]);
        float s = 0.0f, ex[8];
        for (int e = 0; e < 8; ++e) { ex[e] = expf(lgS[e] - mx); s += ex[e]; }
        for (int e = 0; e < 8; ++e) rwS[e] = ex[e] / s;
        int i1 = 0;
        for (int e = 1; e < 8; ++e) if (rwS[e] > rwS[i1]) i1 = e;
        int i2 = (i1 == 0) ? 1 : 0;
        for (int e = 0; e < 8; ++e) if (e != i1 && rwS[e] > rwS[i2]) i2 = e;
        float t0 = rwS[i1], t1 = rwS[i2], sm = t0 + t1;
        TW[b * 2] = t0 / sm; TW[b * 2 + 1] = t1 / sm;
        TI[b * 2] = i1; TI[b * 2 + 1] = i2;
    }
    __syncthreads();
    if (t < 8) {
        atomicAdd(&SRWLOG[t], rwS[t]);       // sum of rw over batch
        atomicAdd(&SRWLOG[8 + t], lgS[t]);   // sum of logits over batch
    }
}

__global__ void aux_kernel(const float* SRWLOG, float* out_aux) {
    if (threadIdx.x == 0 && blockIdx.x == 0) {
        float a = 0.0f;
        for (int e = 0; e < 8; ++e)
            a += (SRWLOG[e] / 128.0f) * (SRWLOG[8 + e] / 128.0f);
        out_aux[0] = 0.01f * 8.0f * a;
    }
}

// ---------------- expert conv1: (2->64, k=7, s=2, p=3) ----------------
__global__ __launch_bounds__(256) void e1_kernel(const float* __restrict__ FFT,
                                                 const float* __restrict__ ew1, const float* __restrict__ eb1,
                                                 const int* __restrict__ TI, float* __restrict__ E1, int k) {
    int idx = blockIdx.x * 256 + threadIdx.x;
    const int total = 128 * 64 * L1LEN;
    int stride = gridDim.x * 256;
    for (; idx < total; idx += stride) {
        int r = idx % L1LEN;
        int o = (idx / L1LEN) & 63;
        int b = idx / (L1LEN * 64);
        int e = TI[b * 2 + k];
        float a = eb1[e * 64 + o];
        const float* w = ew1 + (e * 64 + o) * 14;
        const float* fb = FFT + b * 4098;
        #pragma unroll
        for (int c = 0; c < 2; ++c)
            #pragma unroll
            for (int tt = 0; tt < 7; ++tt) {
                int pos = 2 * r - 3 + tt;
                if (pos >= 0 && pos < NFREQ)
                    a = fmaf(fb[c * NFREQ + pos], w[c * 7 + tt], a);
            }
        E1[idx] = relu_f(a);
    }
}

// ---------------- expert conv2: (64->128, k=5, s=2, p=2) ----------------
// grid (9, 128), block 256 = 64 positions x 4 o-groups (32 o each)
__global__ __launch_bounds__(256) void e2_kernel(const float* __restrict__ E1,
                                                 const float* __restrict__ EW2T, const float* __restrict__ eb2,
                                                 const int* __restrict__ TI, float* __restrict__ E2, int k) {
    __shared__ float sT[64][132];
    int b = blockIdx.y;
    int q0 = blockIdx.x * 64;
    int t = threadIdx.x;
    int e = TI[b * 2 + k];
    for (int i = t; i < 64 * 132; i += 256) {
        int c = i / 132, r = i % 132;
        int pp = 2 * q0 - 2 + r;
        sT[c][r] = (pp >= 0 && pp < L1LEN) ? E1[(b * 64 + c) * L1LEN + pp] : 0.0f;
    }
    __syncthreads();
    int lq = t & 63, q = q0 + lq;
    int og = __builtin_amdgcn_readfirstlane(t >> 6);
    float acc[32];
    #pragma unroll
    for (int i = 0; i < 32; ++i) acc[i] = 0.0f;
    for (int c = 0; c < 64; ++c) {
        #pragma unroll
        for (int tt = 0; tt < 5; ++tt) {
            float xv = sT[c][2 * lq + tt];
            const float* wr = EW2T + e * 40960 + (c * 5 + tt) * 128 + og * 32;
            #pragma unroll
            for (int o = 0; o < 32; ++o) acc[o] = fmaf(wr[o], xv, acc[o]);
        }
    }
    if (q < L2LEN) {
        #pragma unroll
        for (int o = 0; o < 32; ++o) {
            int oo = og * 32 + o;
            E2[(b * 128 + oo) * L2LEN + q] = relu_f(acc[o] + eb2[e * 128 + oo]);
        }
    }
}

// ---------------- expert conv3 + weighted accumulate: (128->128, k=3, s=1, p=1) ----------------
__global__ __launch_bounds__(256) void e3_kernel(const float* __restrict__ E2,
                                                 const float* __restrict__ EW3T, const float* __restrict__ eb3,
                                                 const int* __restrict__ TI, const float* __restrict__ TW,
                                                 float* __restrict__ FINAL, int k) {
    __shared__ float sT[128][66];
    int b = blockIdx.y;
    int q0 = blockIdx.x * 64;
    int t = threadIdx.x;
    int e = TI[b * 2 + k];
    float wk = TW[b * 2 + k];
    for (int i = t; i < 128 * 66; i += 256) {
        int c = i / 66, r = i % 66;
        int pp = q0 - 1 + r;
        sT[c][r] = (pp >= 0 && pp < L2LEN) ? E2[(b * 128 + c) * L2LEN + pp] : 0.0f;
    }
    __syncthreads();
    int lq = t & 63, q = q0 + lq;
    int og = __builtin_amdgcn_readfirstlane(t >> 6);
    float acc[32];
    #pragma unroll
    for (int i = 0; i < 32; ++i) acc[i] = 0.0f;
    for (int c = 0; c < 128; ++c) {
        #pragma unroll
        for (int tt = 0; tt < 3; ++tt) {
            float xv = sT[c][lq + tt];
            const float* wr = EW3T + e * 49152 + (c * 3 + tt) * 128 + og * 32;
            #pragma unroll
            for (int o = 0; o < 32; ++o) acc[o] = fmaf(wr[o], xv, acc[o]);
        }
    }
    if (q < L2LEN) {
        #pragma unroll
        for (int o = 0; o < 32; ++o) {
            int oo = og * 32 + o;
            float v = relu_f(acc[o] + eb3[e * 128 + oo]) * wk;
            int oi = (b * 128 + oo) * L2LEN + q;
            if (k == 0) FINAL[oi] = v;
            else        FINAL[oi] += v;
        }
    }
}

// ---------------- adaptive max-pool 513 -> 256 ----------------
__global__ __launch_bounds__(256) void maxpool_kernel(const float* __restrict__ FINAL, float* __restrict__ out) {
    int idx = blockIdx.x * 256 + threadIdx.x;
    if (idx >= 128 * 128 * 256) return;
    int j = idx & 255;
    int bo = idx >> 8;
    int s = (j * 513) >> 8;
    int e_ = (j * 513 + 768) >> 8;   // ceil((j+1)*513/256)
    const float* f = FINAL + bo * L2LEN;
    float m = f[s];
    if (s + 1 < e_) m = fmaxf(m, f[s + 1]);
    if (s + 2 < e_) m = fmaxf(m, f[s + 2]);
    out[idx] = m;
}

extern "C" void kernel_launch(void* const* d_in, const int* in_sizes, int n_in,
                              void* d_out, int out_size, void* d_ws, size_t ws_size,
                              hipStream_t stream) {
    const float* x    = (const float*)d_in[0];
    const float* g_w1 = (const float*)d_in[1];
    const float* g_b1 = (const float*)d_in[2];
    const float* g_w2 = (const float*)d_in[3];
    const float* g_b2 = (const float*)d_in[4];
    const float* m_w1 = (const float*)d_in[5];
    const float* m_b1 = (const float*)d_in[6];
    const float* m_w2 = (const float*)d_in[7];
    const float* m_b2 = (const float*)d_in[8];
    const float* ew1  = (const float*)d_in[9];
    const float* eb1  = (const float*)d_in[10];
    const float* ew2  = (const float*)d_in[11];
    const float* eb2  = (const float*)d_in[12];
    const float* ew3  = (const float*)d_in[13];
    const float* eb3  = (const float*)d_in[14];

    float* ws     = (float*)d_ws;
    float* FFT    = ws + OFF_FFT;
    float* POOLED = ws + OFF_POOLED;
    float* TW     = ws + OFF_TW;
    int*   TI     = (int*)(ws + OFF_TI);
    float* SRWLOG = ws + OFF_SRWLOG;
    float* W2T    = ws + OFF_W2T;
    float* EW2T   = ws + OFF_EW2T;
    float* EW3T   = ws + OFF_EW3T;
    float* E1     = ws + OFF_E1;
    float* E2     = ws + OFF_E2;
    float* FINAL  = ws + OFF_FINAL;
    float* out    = (float*)d_out;

    init_kernel<<<512, 256, 0, stream>>>(POOLED, SRWLOG, W2T, EW2T, EW3T, g_w2, ew2, ew3);
    fft_kernel<<<128, 256, 0, stream>>>(x, FFT);
    gate_kernel<<<dim3(33, 128), 256, 0, stream>>>(FFT, g_w1, g_b1, W2T, g_b2, POOLED);
    mlp_kernel<<<128, 128, 0, stream>>>(POOLED, m_w1, m_b1, m_w2, m_b2, TW, TI, SRWLOG);
    aux_kernel<<<1, 64, 0, stream>>>(SRWLOG, out + 4194304);
    for (int k = 0; k < 2; ++k) {
        e1_kernel<<<32800, 256, 0, stream>>>(FFT, ew1, eb1, TI, E1, k);
        e2_kernel<<<dim3(9, 128), 256, 0, stream>>>(E1, EW2T, eb2, TI, E2, k);
        e3_kernel<<<dim3(9, 128), 256, 0, stream>>>(E2, EW3T, eb3, TI, TW, FINAL, k);
    }
    maxpool_kernel<<<16384, 256, 0, stream>>>(FINAL, out);
}

// Round 2
// 973.799 us; speedup vs baseline: 1.0076x; 1.0076x over previous
//
#include <hip/hip_runtime.h>

#define NFREQ 2049
#define L1LEN 1025
#define L2LEN 513

// ---------------- workspace layout (float offsets) ----------------
#define OFF_FFT     0ull                 // 128*4098 = 524544
#define OFF_PART    524544ull            // 128*64*33 = 270336
#define OFF_TW      794880ull            // 256
#define OFF_TI      795136ull            // 256 (ints)
#define OFF_SRWLOG  795392ull            // 16
#define OFF_W2T     795408ull            // 10240
#define OFF_EW2T    805648ull            // 327680
#define OFF_EW3T    1133328ull           // 393216
#define OFF_H1E1    1526544ull           // max(8392704, 8396800) = 8396800 (H1 then reused as E1)
#define OFF_E2      9923344ull           // 8404992
#define OFF_FINAL   18328336ull          // 8404992
// total 26,733,328 floats ~ 107 MiB

__device__ __forceinline__ float relu_f(float x) { return fmaxf(x, 0.0f); }
__device__ __forceinline__ int   rfl_i(int v)   { return __builtin_amdgcn_readfirstlane(v); }
__device__ __forceinline__ float rfl_f(float v) { return __uint_as_float((unsigned)__builtin_amdgcn_readfirstlane((int)__float_as_uint(v))); }

// ---------------- init: zero aux accumulators + transpose weights ----------------
__global__ void init_kernel(float* SRWLOG, float* W2T, float* EW2T, float* EW3T,
                            const float* g_w2, const float* ew2, const float* ew3) {
    int tid = blockIdx.x * blockDim.x + threadIdx.x;
    int stride = gridDim.x * blockDim.x;
    for (int i = tid; i < 16; i += stride) SRWLOG[i] = 0.0f;
    // g_w2 (64,32,5) -> W2T[(c*5+t)*64 + o]
    for (int i = tid; i < 10240; i += stride) {
        int ct = i >> 6, o = i & 63;
        W2T[i] = g_w2[o * 160 + ct];
    }
    // ew2 (8,128,64,5) -> EW2T[e*40960 + (c*5+t)*128 + o]
    for (int i = tid; i < 327680; i += stride) {
        int e = i / 40960, r = i % 40960;
        int ct = r >> 7, o = r & 127;
        EW2T[i] = ew2[(e * 128 + o) * 320 + ct];
    }
    // ew3 (8,128,128,3) -> EW3T[e*49152 + (c*3+t)*128 + o]
    for (int i = tid; i < 393216; i += stride) {
        int e = i / 49152, r = i % 49152;
        int ct = r >> 7, o = r & 127;
        EW3T[i] = ew3[(e * 128 + o) * 384 + ct];
    }
}

// ---------------- windowed rfft(4096) via 2048-pt complex FFT ----------------
__global__ __launch_bounds__(256) void fft_kernel(const float* __restrict__ x, float* __restrict__ FFT) {
    __shared__ float re[2048];
    __shared__ float im[2048];
    const float PI = 3.14159265358979323846f;
    int b = blockIdx.x, t = threadIdx.x;
    const float* xb = x + b * 4096;
    const float wstep = 2.0f * PI / 4096.0f;
    for (int i = t; i < 2048; i += 256) {
        int j = (int)(__brev((unsigned)i) >> 21);   // 11-bit reversal
        float w0 = 0.5f * (1.0f - cosf(wstep * (float)(2 * j)));
        float w1 = 0.5f * (1.0f - cosf(wstep * (float)(2 * j + 1)));
        re[i] = xb[2 * j] * w0;
        im[i] = xb[2 * j + 1] * w1;
    }
    for (int s = 1; s <= 11; ++s) {
        __syncthreads();
        int half = 1 << (s - 1);
        for (int bf = t; bf < 1024; bf += 256) {
            int grp = bf >> (s - 1);
            int pos = bf & (half - 1);
            int i1 = (grp << s) + pos;
            int i2 = i1 + half;
            float ang = -PI * (float)pos / (float)half;
            float wr = cosf(ang), wi = sinf(ang);
            float ar = re[i2], ai = im[i2];
            float tr = wr * ar - wi * ai;
            float ti = wr * ai + wi * ar;
            float br = re[i1], bi = im[i1];
            re[i2] = br - tr; im[i2] = bi - ti;
            re[i1] = br + tr; im[i1] = bi + ti;
        }
    }
    __syncthreads();
    const float scale = 1.0f / 64.0f;
    for (int k = t; k <= 2048; k += 256) {
        int k1 = k & 2047;
        int k2 = (2048 - k) & 2047;
        float zr = re[k1], zi = im[k1];
        float yr = re[k2], yi = im[k2];
        float Er = 0.5f * (zr + yr), Ei = 0.5f * (zi - yi);
        float Or = 0.5f * (zi + yi), Oi = 0.5f * (yr - zr);
        float th = PI * (float)k / 2048.0f;
        float c2 = cosf(th), s3 = sinf(th);
        float Xr = (Er + c2 * Or + s3 * Oi) * scale;
        float Xi = (Ei + c2 * Oi - s3 * Or) * scale;
        FFT[b * 4098 + k] = Xr;
        FFT[b * 4098 + 2049 + k] = Xi;
    }
}

// ---------------- gate conv1: (2->32, k=5, s=1, p=2) -> H1 ----------------
// grid (chunks=9, o=32, b=128): o block-uniform -> scalar weight loads
__global__ __launch_bounds__(256) void g1_kernel(const float* __restrict__ FFT,
                                                 const float* __restrict__ g_w1, const float* __restrict__ g_b1,
                                                 float* __restrict__ H1) {
    int r = blockIdx.x * 256 + threadIdx.x;
    if (r >= NFREQ) return;
    int o = blockIdx.y;
    int b = blockIdx.z;
    const float* fb = FFT + b * 4098;
    const float* w = g_w1 + o * 10;
    float a = g_b1[o];
    #pragma unroll
    for (int cc = 0; cc < 2; ++cc)
        #pragma unroll
        for (int tt = 0; tt < 5; ++tt) {
            int pos = r - 2 + tt;
            if (pos >= 0 && pos < NFREQ)
                a = fmaf(fb[cc * NFREQ + pos], w[cc * 5 + tt], a);
        }
    H1[(b * 32 + o) * NFREQ + r] = relu_f(a);
}

// ---------------- gate conv2 + partial mean-pool (32->64, k=5, s=1, p=2) ----------------
// grid (33, 128), block 256 = 64 positions x 4 o-groups (16 o each); e2-structured.
__global__ __launch_bounds__(256) void g2_kernel(const float* __restrict__ H1,
                                                 const float* __restrict__ W2T, const float* __restrict__ g_b2,
                                                 float* __restrict__ PART) {
    __shared__ float sT[32][68];
    int b = blockIdx.y;
    int p0 = blockIdx.x * 64;
    int t = threadIdx.x;
    for (int i = t; i < 32 * 68; i += 256) {
        int c = i / 68, r = i % 68;
        int pos = p0 - 2 + r;
        sT[c][r] = (pos >= 0 && pos < NFREQ) ? H1[(b * 32 + c) * NFREQ + pos] : 0.0f;
    }
    __syncthreads();
    int lq = t & 63;
    int q = p0 + lq;
    int og = rfl_i(t >> 6);
    float acc[16];
    #pragma unroll
    for (int i = 0; i < 16; ++i) acc[i] = 0.0f;
    for (int c = 0; c < 32; ++c) {
        #pragma unroll
        for (int tt = 0; tt < 5; ++tt) {
            float xv = sT[c][lq + tt];
            const float* wr = W2T + (c * 5 + tt) * 64 + og * 16;
            #pragma unroll
            for (int o = 0; o < 16; ++o) acc[o] = fmaf(wr[o], xv, acc[o]);
        }
    }
    bool valid = (q < NFREQ);
    #pragma unroll
    for (int o = 0; o < 16; ++o) {
        float v = valid ? relu_f(acc[o] + g_b2[og * 16 + o]) : 0.0f;
        #pragma unroll
        for (int m = 32; m >= 1; m >>= 1) v += __shfl_xor(v, m, 64);
        if (lq == 0) PART[(b * 64 + og * 16 + o) * 33 + blockIdx.x] = v;
    }
}

// ---------------- router MLP (reduces PART) + softmax + top2 + aux partials ----------------
__global__ __launch_bounds__(128) void mlp_kernel(const float* __restrict__ PART,
                                                  const float* __restrict__ m_w1, const float* __restrict__ m_b1,
                                                  const float* __restrict__ m_w2, const float* __restrict__ m_b2,
                                                  float* TW, int* TI, float* SRWLOG) {
    __shared__ float pooledS[64];
    __shared__ float hid[128];
    __shared__ float lgS[8];
    __shared__ float rwS[8];
    int b = blockIdx.x, t = threadIdx.x;
    if (t < 64) {
        float s = 0.0f;
        const float* pp = PART + (b * 64 + t) * 33;
        for (int blk = 0; blk < 33; ++blk) s += pp[blk];
        pooledS[t] = s;
    }
    __syncthreads();
    const float inv = 1.0f / 2049.0f;
    {
        float h = m_b1[t];
        for (int c = 0; c < 64; ++c)
            h = fmaf(pooledS[c] * inv, m_w1[t * 64 + c], h);
        hid[t] = relu_f(h);
    }
    __syncthreads();
    if (t < 8) {
        float lg = m_b2[t];
        for (int j = 0; j < 128; ++j) lg = fmaf(hid[j], m_w2[t * 128 + j], lg);
        lgS[t] = lg;
    }
    __syncthreads();
    if (t == 0) {
        float mx = lgS[0];
        for (int e = 1; e < 8; ++e) mx = fmaxf(mx, lgS[e]);
        float s = 0.0f, ex[8];
        for (int e = 0; e < 8; ++e) { ex[e] = expf(lgS[e] - mx); s += ex[e]; }
        for (int e = 0; e < 8; ++e) rwS[e] = ex[e] / s;
        int i1 = 0;
        for (int e = 1; e < 8; ++e) if (rwS[e] > rwS[i1]) i1 = e;
        int i2 = (i1 == 0) ? 1 : 0;
        for (int e = 0; e < 8; ++e) if (e != i1 && rwS[e] > rwS[i2]) i2 = e;
        float t0 = rwS[i1], t1 = rwS[i2], sm = t0 + t1;
        TW[b * 2] = t0 / sm; TW[b * 2 + 1] = t1 / sm;
        TI[b * 2] = i1; TI[b * 2 + 1] = i2;
    }
    __syncthreads();
    if (t < 8) {
        atomicAdd(&SRWLOG[t], rwS[t]);
        atomicAdd(&SRWLOG[8 + t], lgS[t]);
    }
}

__global__ void aux_kernel(const float* SRWLOG, float* out_aux) {
    if (threadIdx.x == 0 && blockIdx.x == 0) {
        float a = 0.0f;
        for (int e = 0; e < 8; ++e)
            a += (SRWLOG[e] / 128.0f) * (SRWLOG[8 + e] / 128.0f);
        out_aux[0] = 0.01f * 8.0f * a;
    }
}

// ---------------- expert conv1: (2->64, k=7, s=2, p=3) ----------------
// grid (chunks=5, o=64, b=128): o block-uniform, e scalar -> scalar weight loads
__global__ __launch_bounds__(256) void e1_kernel(const float* __restrict__ FFT,
                                                 const float* __restrict__ ew1, const float* __restrict__ eb1,
                                                 const int* __restrict__ TI, float* __restrict__ E1, int k) {
    int r = blockIdx.x * 256 + threadIdx.x;
    if (r >= L1LEN) return;
    int o = blockIdx.y;
    int b = blockIdx.z;
    int e = rfl_i(TI[b * 2 + k]);
    const float* fb = FFT + b * 4098;
    const float* w = ew1 + (e * 64 + o) * 14;
    float a = eb1[e * 64 + o];
    #pragma unroll
    for (int c = 0; c < 2; ++c)
        #pragma unroll
        for (int tt = 0; tt < 7; ++tt) {
            int pos = 2 * r - 3 + tt;
            if (pos >= 0 && pos < NFREQ)
                a = fmaf(fb[c * NFREQ + pos], w[c * 7 + tt], a);
        }
    E1[(b * 64 + o) * L1LEN + r] = relu_f(a);
}

// ---------------- expert conv2: (64->128, k=5, s=2, p=2) ----------------
// grid (9, 128), block 256 = 64 positions x 4 o-groups (32 o each)
__global__ __launch_bounds__(256) void e2_kernel(const float* __restrict__ E1,
                                                 const float* __restrict__ EW2T, const float* __restrict__ eb2,
                                                 const int* __restrict__ TI, float* __restrict__ E2, int k) {
    __shared__ float sT[64][132];
    int b = blockIdx.y;
    int q0 = blockIdx.x * 64;
    int t = threadIdx.x;
    int e = rfl_i(TI[b * 2 + k]);
    for (int i = t; i < 64 * 132; i += 256) {
        int c = i / 132, r = i % 132;
        int pp = 2 * q0 - 2 + r;
        sT[c][r] = (pp >= 0 && pp < L1LEN) ? E1[(b * 64 + c) * L1LEN + pp] : 0.0f;
    }
    __syncthreads();
    int lq = t & 63, q = q0 + lq;
    int og = rfl_i(t >> 6);
    float acc[32];
    #pragma unroll
    for (int i = 0; i < 32; ++i) acc[i] = 0.0f;
    const float* wbase = EW2T + e * 40960 + og * 32;
    for (int c = 0; c < 64; ++c) {
        #pragma unroll
        for (int tt = 0; tt < 5; ++tt) {
            float xv = sT[c][2 * lq + tt];
            const float* wr = wbase + (c * 5 + tt) * 128;
            #pragma unroll
            for (int o = 0; o < 32; ++o) acc[o] = fmaf(wr[o], xv, acc[o]);
        }
    }
    if (q < L2LEN) {
        #pragma unroll
        for (int o = 0; o < 32; ++o) {
            int oo = og * 32 + o;
            E2[(b * 128 + oo) * L2LEN + q] = relu_f(acc[o] + eb2[e * 128 + oo]);
        }
    }
}

// ---------------- expert conv3 + weighted accumulate: (128->128, k=3, s=1, p=1) ----------------
__global__ __launch_bounds__(256) void e3_kernel(const float* __restrict__ E2,
                                                 const float* __restrict__ EW3T, const float* __restrict__ eb3,
                                                 const int* __restrict__ TI, const float* __restrict__ TW,
                                                 float* __restrict__ FINAL, int k) {
    __shared__ float sT[128][66];
    int b = blockIdx.y;
    int q0 = blockIdx.x * 64;
    int t = threadIdx.x;
    int e = rfl_i(TI[b * 2 + k]);
    float wk = rfl_f(TW[b * 2 + k]);
    for (int i = t; i < 128 * 66; i += 256) {
        int c = i / 66, r = i % 66;
        int pp = q0 - 1 + r;
        sT[c][r] = (pp >= 0 && pp < L2LEN) ? E2[(b * 128 + c) * L2LEN + pp] : 0.0f;
    }
    __syncthreads();
    int lq = t & 63, q = q0 + lq;
    int og = rfl_i(t >> 6);
    float acc[32];
    #pragma unroll
    for (int i = 0; i < 32; ++i) acc[i] = 0.0f;
    const float* wbase = EW3T + e * 49152 + og * 32;
    for (int c = 0; c < 128; ++c) {
        #pragma unroll
        for (int tt = 0; tt < 3; ++tt) {
            float xv = sT[c][lq + tt];
            const float* wr = wbase + (c * 3 + tt) * 128;
            #pragma unroll
            for (int o = 0; o < 32; ++o) acc[o] = fmaf(wr[o], xv, acc[o]);
        }
    }
    if (q < L2LEN) {
        #pragma unroll
        for (int o = 0; o < 32; ++o) {
            int oo = og * 32 + o;
            float v = relu_f(acc[o] + eb3[e * 128 + oo]) * wk;
            int oi = (b * 128 + oo) * L2LEN + q;
            if (k == 0) FINAL[oi] = v;
            else        FINAL[oi] += v;
        }
    }
}

// ---------------- adaptive max-pool 513 -> 256 ----------------
__global__ __launch_bounds__(256) void maxpool_kernel(const float* __restrict__ FINAL, float* __restrict__ out) {
    int idx = blockIdx.x * 256 + threadIdx.x;
    if (idx >= 128 * 128 * 256) return;
    int j = idx & 255;
    int bo = idx >> 8;
    int s = (j * 513) >> 8;
    int e_ = (j * 513 + 768) >> 8;   // ceil((j+1)*513/256)
    const float* f = FINAL + bo * L2LEN;
    float m = f[s];
    if (s + 1 < e_) m = fmaxf(m, f[s + 1]);
    if (s + 2 < e_) m = fmaxf(m, f[s + 2]);
    out[idx] = m;
}

extern "C" void kernel_launch(void* const* d_in, const int* in_sizes, int n_in,
                              void* d_out, int out_size, void* d_ws, size_t ws_size,
                              hipStream_t stream) {
    const float* x    = (const float*)d_in[0];
    const float* g_w1 = (const float*)d_in[1];
    const float* g_b1 = (const float*)d_in[2];
    const float* g_w2 = (const float*)d_in[3];
    const float* g_b2 = (const float*)d_in[4];
    const float* m_w1 = (const float*)d_in[5];
    const float* m_b1 = (const float*)d_in[6];
    const float* m_w2 = (const float*)d_in[7];
    const float* m_b2 = (const float*)d_in[8];
    const float* ew1  = (const float*)d_in[9];
    const float* eb1  = (const float*)d_in[10];
    const float* ew2  = (const float*)d_in[11];
    const float* eb2  = (const float*)d_in[12];
    const float* ew3  = (const float*)d_in[13];
    const float* eb3  = (const float*)d_in[14];

    float* ws     = (float*)d_ws;
    float* FFT    = ws + OFF_FFT;
    float* PART   = ws + OFF_PART;
    float* TW     = ws + OFF_TW;
    int*   TI     = (int*)(ws + OFF_TI);
    float* SRWLOG = ws + OFF_SRWLOG;
    float* W2T    = ws + OFF_W2T;
    float* EW2T   = ws + OFF_EW2T;
    float* EW3T   = ws + OFF_EW3T;
    float* H1     = ws + OFF_H1E1;   // gate conv1 output, dead after g2
    float* E1     = ws + OFF_H1E1;   // reuses H1 space
    float* E2     = ws + OFF_E2;
    float* FINAL  = ws + OFF_FINAL;
    float* out    = (float*)d_out;

    init_kernel<<<512, 256, 0, stream>>>(SRWLOG, W2T, EW2T, EW3T, g_w2, ew2, ew3);
    fft_kernel<<<128, 256, 0, stream>>>(x, FFT);
    g1_kernel<<<dim3(9, 32, 128), 256, 0, stream>>>(FFT, g_w1, g_b1, H1);
    g2_kernel<<<dim3(33, 128), 256, 0, stream>>>(H1, W2T, g_b2, PART);
    mlp_kernel<<<128, 128, 0, stream>>>(PART, m_w1, m_b1, m_w2, m_b2, TW, TI, SRWLOG);
    aux_kernel<<<1, 64, 0, stream>>>(SRWLOG, out + 4194304);
    for (int k = 0; k < 2; ++k) {
        e1_kernel<<<dim3(5, 64, 128), 256, 0, stream>>>(FFT, ew1, eb1, TI, E1, k);
        e2_kernel<<<dim3(9, 128), 256, 0, stream>>>(E1, EW2T, eb2, TI, E2, k);
        e3_kernel<<<dim3(9, 128), 256, 0, stream>>>(E2, EW3T, eb3, TI, TW, FINAL, k);
    }
    maxpool_kernel<<<16384, 256, 0, stream>>>(FINAL, out);
}

// Round 3
// 515.657 us; speedup vs baseline: 1.9027x; 1.8885x over previous
//
#include <hip/hip_runtime.h>

#define NFREQ 2049
#define L1LEN 1025
#define L2LEN 513

typedef short v8s  __attribute__((ext_vector_type(8)));
typedef float v16f __attribute__((ext_vector_type(16)));
typedef unsigned short ushort_t;

// ---------------- workspace layout (float offsets) ----------------
#define OFF_FFT     0ull          // 524544
#define OFF_PART    524544ull     // 270336
#define OFF_TW      794880ull     // 256
#define OFF_TI      795136ull     // 256 (ints)
#define OFF_SRWLOG  795392ull     // 16
#define OFF_W2T     795408ull     // 10240  (fp32, for g2)
#define OFF_W2P     805648ull     // 163840 (ushort 327680: bf16 [e][t][o][c] 8*5*128*64)
#define OFF_W3P     969488ull     // 196608 (ushort 393216: bf16 [e][t][o][c] 8*3*128*128)
#define OFF_H1E1    1166096ull    // 8392704 f32 H1; reused as E1u ushort 8396800 (=4198400 fl)
#define OFF_E2U     9558800ull    // 4202496 (ushort 8404992)
#define OFF_FINAL   13761296ull   // 8404992
// total 22,166,288 floats ~ 85 MiB

__device__ __forceinline__ float relu_f(float x) { return fmaxf(x, 0.0f); }
__device__ __forceinline__ int   rfl_i(int v)   { return __builtin_amdgcn_readfirstlane(v); }
__device__ __forceinline__ float rfl_f(float v) { return __uint_as_float((unsigned)__builtin_amdgcn_readfirstlane((int)__float_as_uint(v))); }
__device__ __forceinline__ ushort_t f2bf(float x) {
    unsigned u = __float_as_uint(x);
    unsigned r = (u + 0x7FFFu + ((u >> 16) & 1u)) >> 16;   // RNE
    return (ushort_t)r;
}

// ---------------- init: zero aux + pack weights ----------------
__global__ void init_kernel(float* SRWLOG, float* W2T, ushort_t* W2P, ushort_t* W3P,
                            const float* g_w2, const float* ew2, const float* ew3) {
    int tid = blockIdx.x * blockDim.x + threadIdx.x;
    int stride = gridDim.x * blockDim.x;
    for (int i = tid; i < 16; i += stride) SRWLOG[i] = 0.0f;
    // g_w2 (64,32,5) -> W2T[(c*5+t)*64 + o]  (fp32, gate conv2)
    for (int i = tid; i < 10240; i += stride) {
        int ct = i >> 6, o = i & 63;
        W2T[i] = g_w2[o * 160 + ct];
    }
    // ew2 (8,128,64,5) -> W2P[((e*5+t)*128+o)*64 + c] bf16
    for (int i = tid; i < 327680; i += stride) {
        int c = i & 63;
        int o = (i >> 6) & 127;
        int t = (i >> 13) % 5;
        int e = i / 40960;
        W2P[i] = f2bf(ew2[((e * 128 + o) * 64 + c) * 5 + t]);
    }
    // ew3 (8,128,128,3) -> W3P[((e*3+t)*128+o)*128 + c] bf16
    for (int i = tid; i < 393216; i += stride) {
        int c = i & 127;
        int o = (i >> 7) & 127;
        int t = (i >> 14) % 3;
        int e = i / 49152;
        W3P[i] = f2bf(ew3[((e * 128 + o) * 128 + c) * 3 + t]);
    }
}

// ---------------- windowed rfft(4096) via 2048-pt complex FFT ----------------
__global__ __launch_bounds__(256) void fft_kernel(const float* __restrict__ x, float* __restrict__ FFT) {
    __shared__ float re[2048];
    __shared__ float im[2048];
    const float PI = 3.14159265358979323846f;
    int b = blockIdx.x, t = threadIdx.x;
    const float* xb = x + b * 4096;
    const float wstep = 2.0f * PI / 4096.0f;
    for (int i = t; i < 2048; i += 256) {
        int j = (int)(__brev((unsigned)i) >> 21);
        float w0 = 0.5f * (1.0f - cosf(wstep * (float)(2 * j)));
        float w1 = 0.5f * (1.0f - cosf(wstep * (float)(2 * j + 1)));
        re[i] = xb[2 * j] * w0;
        im[i] = xb[2 * j + 1] * w1;
    }
    for (int s = 1; s <= 11; ++s) {
        __syncthreads();
        int half = 1 << (s - 1);
        for (int bf = t; bf < 1024; bf += 256) {
            int grp = bf >> (s - 1);
            int pos = bf & (half - 1);
            int i1 = (grp << s) + pos;
            int i2 = i1 + half;
            float ang = -PI * (float)pos / (float)half;
            float wr = cosf(ang), wi = sinf(ang);
            float ar = re[i2], ai = im[i2];
            float tr = wr * ar - wi * ai;
            float ti = wr * ai + wi * ar;
            float br = re[i1], bi = im[i1];
            re[i2] = br - tr; im[i2] = bi - ti;
            re[i1] = br + tr; im[i1] = bi + ti;
        }
    }
    __syncthreads();
    const float scale = 1.0f / 64.0f;
    for (int k = t; k <= 2048; k += 256) {
        int k1 = k & 2047;
        int k2 = (2048 - k) & 2047;
        float zr = re[k1], zi = im[k1];
        float yr = re[k2], yi = im[k2];
        float Er = 0.5f * (zr + yr), Ei = 0.5f * (zi - yi);
        float Or = 0.5f * (zi + yi), Oi = 0.5f * (yr - zr);
        float th = PI * (float)k / 2048.0f;
        float c2 = cosf(th), s3 = sinf(th);
        FFT[b * 4098 + k]        = (Er + c2 * Or + s3 * Oi) * scale;
        FFT[b * 4098 + 2049 + k] = (Ei + c2 * Oi - s3 * Or) * scale;
    }
}

// ---------------- gate conv1 ----------------
__global__ __launch_bounds__(256) void g1_kernel(const float* __restrict__ FFT,
                                                 const float* __restrict__ g_w1, const float* __restrict__ g_b1,
                                                 float* __restrict__ H1) {
    int r = blockIdx.x * 256 + threadIdx.x;
    if (r >= NFREQ) return;
    int o = blockIdx.y;
    int b = blockIdx.z;
    const float* fb = FFT + b * 4098;
    const float* w = g_w1 + o * 10;
    float a = g_b1[o];
    #pragma unroll
    for (int cc = 0; cc < 2; ++cc)
        #pragma unroll
        for (int tt = 0; tt < 5; ++tt) {
            int pos = r - 2 + tt;
            if (pos >= 0 && pos < NFREQ)
                a = fmaf(fb[cc * NFREQ + pos], w[cc * 5 + tt], a);
        }
    H1[(b * 32 + o) * NFREQ + r] = relu_f(a);
}

// ---------------- gate conv2 + partial mean-pool ----------------
__global__ __launch_bounds__(256) void g2_kernel(const float* __restrict__ H1,
                                                 const float* __restrict__ W2T, const float* __restrict__ g_b2,
                                                 float* __restrict__ PART) {
    __shared__ float sT[32][68];
    int b = blockIdx.y;
    int p0 = blockIdx.x * 64;
    int t = threadIdx.x;
    for (int i = t; i < 32 * 68; i += 256) {
        int c = i / 68, r = i % 68;
        int pos = p0 - 2 + r;
        sT[c][r] = (pos >= 0 && pos < NFREQ) ? H1[(b * 32 + c) * NFREQ + pos] : 0.0f;
    }
    __syncthreads();
    int lq = t & 63;
    int q = p0 + lq;
    int og = rfl_i(t >> 6);
    float acc[16];
    #pragma unroll
    for (int i = 0; i < 16; ++i) acc[i] = 0.0f;
    for (int c = 0; c < 32; ++c) {
        #pragma unroll
        for (int tt = 0; tt < 5; ++tt) {
            float xv = sT[c][lq + tt];
            const float* wr = W2T + (c * 5 + tt) * 64 + og * 16;
            #pragma unroll
            for (int o = 0; o < 16; ++o) acc[o] = fmaf(wr[o], xv, acc[o]);
        }
    }
    bool valid = (q < NFREQ);
    #pragma unroll
    for (int o = 0; o < 16; ++o) {
        float v = valid ? relu_f(acc[o] + g_b2[og * 16 + o]) : 0.0f;
        #pragma unroll
        for (int m = 32; m >= 1; m >>= 1) v += __shfl_xor(v, m, 64);
        if (lq == 0) PART[(b * 64 + og * 16 + o) * 33 + blockIdx.x] = v;
    }
}

// ---------------- router MLP + softmax + top2 + aux partials ----------------
__global__ __launch_bounds__(128) void mlp_kernel(const float* __restrict__ PART,
                                                  const float* __restrict__ m_w1, const float* __restrict__ m_b1,
                                                  const float* __restrict__ m_w2, const float* __restrict__ m_b2,
                                                  float* TW, int* TI, float* SRWLOG) {
    __shared__ float pooledS[64];
    __shared__ float hid[128];
    __shared__ float lgS[8];
    __shared__ float rwS[8];
    int b = blockIdx.x, t = threadIdx.x;
    if (t < 64) {
        float s = 0.0f;
        const float* pp = PART + (b * 64 + t) * 33;
        for (int blk = 0; blk < 33; ++blk) s += pp[blk];
        pooledS[t] = s;
    }
    __syncthreads();
    const float inv = 1.0f / 2049.0f;
    {
        float h = m_b1[t];
        for (int c = 0; c < 64; ++c)
            h = fmaf(pooledS[c] * inv, m_w1[t * 64 + c], h);
        hid[t] = relu_f(h);
    }
    __syncthreads();
    if (t < 8) {
        float lg = m_b2[t];
        for (int j = 0; j < 128; ++j) lg = fmaf(hid[j], m_w2[t * 128 + j], lg);
        lgS[t] = lg;
    }
    __syncthreads();
    if (t == 0) {
        float mx = lgS[0];
        for (int e = 1; e < 8; ++e) mx = fmaxf(mx, lgS[e]);
        float s = 0.0f, ex[8];
        for (int e = 0; e < 8; ++e) { ex[e] = expf(lgS[e] - mx); s += ex[e]; }
        for (int e = 0; e < 8; ++e) rwS[e] = ex[e] / s;
        int i1 = 0;
        for (int e = 1; e < 8; ++e) if (rwS[e] > rwS[i1]) i1 = e;
        int i2 = (i1 == 0) ? 1 : 0;
        for (int e = 0; e < 8; ++e) if (e != i1 && rwS[e] > rwS[i2]) i2 = e;
        float t0 = rwS[i1], t1 = rwS[i2], sm = t0 + t1;
        TW[b * 2] = t0 / sm; TW[b * 2 + 1] = t1 / sm;
        TI[b * 2] = i1; TI[b * 2 + 1] = i2;
    }
    __syncthreads();
    if (t < 8) {
        atomicAdd(&SRWLOG[t], rwS[t]);
        atomicAdd(&SRWLOG[8 + t], lgS[t]);
    }
}

__global__ void aux_kernel(const float* SRWLOG, float* out_aux) {
    if (threadIdx.x == 0 && blockIdx.x == 0) {
        float a = 0.0f;
        for (int e = 0; e < 8; ++e)
            a += (SRWLOG[e] / 128.0f) * (SRWLOG[8 + e] / 128.0f);
        out_aux[0] = 0.01f * 8.0f * a;
    }
}

// ---------------- expert conv1: (2->64, k=7, s=2, p=3), bf16 out ----------------
__global__ __launch_bounds__(256) void e1_kernel(const float* __restrict__ FFT,
                                                 const float* __restrict__ ew1, const float* __restrict__ eb1,
                                                 const int* __restrict__ TI, ushort_t* __restrict__ E1u, int k) {
    int r = blockIdx.x * 256 + threadIdx.x;
    if (r >= L1LEN) return;
    int o = blockIdx.y;
    int b = blockIdx.z;
    int e = rfl_i(TI[b * 2 + k]);
    const float* fb = FFT + b * 4098;
    const float* w = ew1 + (e * 64 + o) * 14;
    float a = eb1[e * 64 + o];
    #pragma unroll
    for (int c = 0; c < 2; ++c)
        #pragma unroll
        for (int tt = 0; tt < 7; ++tt) {
            int pos = 2 * r - 3 + tt;
            if (pos >= 0 && pos < NFREQ)
                a = fmaf(fb[c * NFREQ + pos], w[c * 7 + tt], a);
        }
    E1u[(b * 64 + o) * L1LEN + r] = f2bf(relu_f(a));
}

// ---------------- expert conv2 (MFMA): (64->128, k=5, s=2, p=2) ----------------
// grid (9, 128); block 256 = 4 waves; wave w -> o-tile w*32; q-tile 64 (2 mfma cols)
__global__ __launch_bounds__(256) void e2_kernel(const ushort_t* __restrict__ E1u,
                                                 const ushort_t* __restrict__ W2P, const float* __restrict__ eb2,
                                                 const int* __restrict__ TI, ushort_t* __restrict__ E2u, int k) {
    __shared__ ushort_t xe[66][68];   // even positions: xe[r][c] = E1[c][2*(q0-1+r)]
    __shared__ ushort_t xo[66][68];   // odd:  xo[r][c] = E1[c][2*(q0-1+r)+1]
    int b = blockIdx.y;
    int q0 = blockIdx.x * 64;
    int t = threadIdx.x;
    int e = rfl_i(TI[b * 2 + k]);
    // stage 132 positions x 64 channels
    for (int i = t; i < 64 * 132; i += 256) {
        int c = i / 132, poff = i % 132;
        int pos = 2 * q0 - 2 + poff;
        ushort_t v = (pos >= 0 && pos < L1LEN) ? E1u[(b * 64 + c) * L1LEN + pos] : (ushort_t)0;
        int row = poff >> 1;
        if (poff & 1) xo[row][c] = v; else xe[row][c] = v;
    }
    __syncthreads();
    int lane = t & 63;
    int w = rfl_i(t >> 6);
    int n = lane & 31;
    int kg = lane >> 5;
    v16f acc0, acc1;
    #pragma unroll
    for (int i = 0; i < 16; ++i) { acc0[i] = 0.0f; acc1[i] = 0.0f; }
    #pragma unroll
    for (int t5 = 0; t5 < 5; ++t5) {
        const ushort_t* wrow = W2P + (((e * 5 + t5) * 128) + w * 32 + n) * 64;
        int roff = t5 >> 1;
        const ushort_t (*sel)[68] = (t5 & 1) ? xo : xe;
        #pragma unroll
        for (int ks = 0; ks < 4; ++ks) {
            int c0 = ks * 16 + kg * 8;
            v8s a = *(const v8s*)(wrow + c0);
            union { uint2 u[2]; v8s v; } b0u, b1u;
            const uint2* p0 = (const uint2*)&sel[n + roff][c0];
            const uint2* p1 = (const uint2*)&sel[n + 32 + roff][c0];
            b0u.u[0] = p0[0]; b0u.u[1] = p0[1];
            b1u.u[0] = p1[0]; b1u.u[1] = p1[1];
            acc0 = __builtin_amdgcn_mfma_f32_32x32x16_bf16(a, b0u.v, acc0, 0, 0, 0);
            acc1 = __builtin_amdgcn_mfma_f32_32x32x16_bf16(a, b1u.v, acc1, 0, 0, 0);
        }
    }
    #pragma unroll
    for (int r = 0; r < 16; ++r) {
        int m = (r & 3) + 8 * (r >> 2) + 4 * kg;
        int o = w * 32 + m;
        float bias = eb2[e * 128 + o];
        int q = q0 + n;
        if (q < L2LEN)      E2u[(b * 128 + o) * L2LEN + q]      = f2bf(relu_f(acc0[r] + bias));
        int q2 = q0 + 32 + n;
        if (q2 < L2LEN)     E2u[(b * 128 + o) * L2LEN + q2]     = f2bf(relu_f(acc1[r] + bias));
    }
}

// ---------------- expert conv3 (MFMA) + weighted accumulate: (128->128, k=3, s=1, p=1) ----------------
__global__ __launch_bounds__(256) void e3_kernel(const ushort_t* __restrict__ E2u,
                                                 const ushort_t* __restrict__ W3P, const float* __restrict__ eb3,
                                                 const int* __restrict__ TI, const float* __restrict__ TW,
                                                 float* __restrict__ FINAL, int k) {
    __shared__ ushort_t xT[66][132];  // xT[r][c] = E2[c][q0-1+r]
    int b = blockIdx.y;
    int q0 = blockIdx.x * 64;
    int t = threadIdx.x;
    int e = rfl_i(TI[b * 2 + k]);
    float wk = rfl_f(TW[b * 2 + k]);
    for (int i = t; i < 128 * 66; i += 256) {
        int c = i / 66, row = i % 66;
        int pos = q0 - 1 + row;
        xT[row][c] = (pos >= 0 && pos < L2LEN) ? E2u[(b * 128 + c) * L2LEN + pos] : (ushort_t)0;
    }
    __syncthreads();
    int lane = t & 63;
    int w = rfl_i(t >> 6);
    int n = lane & 31;
    int kg = lane >> 5;
    v16f acc0, acc1;
    #pragma unroll
    for (int i = 0; i < 16; ++i) { acc0[i] = 0.0f; acc1[i] = 0.0f; }
    #pragma unroll
    for (int t3 = 0; t3 < 3; ++t3) {
        const ushort_t* wrow = W3P + (((e * 3 + t3) * 128) + w * 32 + n) * 128;
        #pragma unroll
        for (int ks = 0; ks < 8; ++ks) {
            int c0 = ks * 16 + kg * 8;
            v8s a = *(const v8s*)(wrow + c0);
            union { uint2 u[2]; v8s v; } b0u, b1u;
            const uint2* p0 = (const uint2*)&xT[n + t3][c0];
            const uint2* p1 = (const uint2*)&xT[n + 32 + t3][c0];
            b0u.u[0] = p0[0]; b0u.u[1] = p0[1];
            b1u.u[0] = p1[0]; b1u.u[1] = p1[1];
            acc0 = __builtin_amdgcn_mfma_f32_32x32x16_bf16(a, b0u.v, acc0, 0, 0, 0);
            acc1 = __builtin_amdgcn_mfma_f32_32x32x16_bf16(a, b1u.v, acc1, 0, 0, 0);
        }
    }
    #pragma unroll
    for (int r = 0; r < 16; ++r) {
        int m = (r & 3) + 8 * (r >> 2) + 4 * kg;
        int o = w * 32 + m;
        float bias = eb3[e * 128 + o];
        int q = q0 + n;
        if (q < L2LEN) {
            float v = relu_f(acc0[r] + bias) * wk;
            int oi = (b * 128 + o) * L2LEN + q;
            if (k == 0) FINAL[oi] = v; else FINAL[oi] += v;
        }
        int q2 = q0 + 32 + n;
        if (q2 < L2LEN) {
            float v = relu_f(acc1[r] + bias) * wk;
            int oi = (b * 128 + o) * L2LEN + q2;
            if (k == 0) FINAL[oi] = v; else FINAL[oi] += v;
        }
    }
}

// ---------------- adaptive max-pool 513 -> 256 ----------------
__global__ __launch_bounds__(256) void maxpool_kernel(const float* __restrict__ FINAL, float* __restrict__ out) {
    int idx = blockIdx.x * 256 + threadIdx.x;
    if (idx >= 128 * 128 * 256) return;
    int j = idx & 255;
    int bo = idx >> 8;
    int s = (j * 513) >> 8;
    int e_ = (j * 513 + 768) >> 8;
    const float* f = FINAL + bo * L2LEN;
    float m = f[s];
    if (s + 1 < e_) m = fmaxf(m, f[s + 1]);
    if (s + 2 < e_) m = fmaxf(m, f[s + 2]);
    out[idx] = m;
}

extern "C" void kernel_launch(void* const* d_in, const int* in_sizes, int n_in,
                              void* d_out, int out_size, void* d_ws, size_t ws_size,
                              hipStream_t stream) {
    const float* x    = (const float*)d_in[0];
    const float* g_w1 = (const float*)d_in[1];
    const float* g_b1 = (const float*)d_in[2];
    const float* g_w2 = (const float*)d_in[3];
    const float* g_b2 = (const float*)d_in[4];
    const float* m_w1 = (const float*)d_in[5];
    const float* m_b1 = (const float*)d_in[6];
    const float* m_w2 = (const float*)d_in[7];
    const float* m_b2 = (const float*)d_in[8];
    const float* ew1  = (const float*)d_in[9];
    const float* eb1  = (const float*)d_in[10];
    const float* ew2  = (const float*)d_in[11];
    const float* eb2  = (const float*)d_in[12];
    const float* ew3  = (const float*)d_in[13];
    const float* eb3  = (const float*)d_in[14];

    float* ws     = (float*)d_ws;
    float* FFT    = ws + OFF_FFT;
    float* PART   = ws + OFF_PART;
    float* TW     = ws + OFF_TW;
    int*   TI     = (int*)(ws + OFF_TI);
    float* SRWLOG = ws + OFF_SRWLOG;
    float* W2T    = ws + OFF_W2T;
    ushort_t* W2P = (ushort_t*)(ws + OFF_W2P);
    ushort_t* W3P = (ushort_t*)(ws + OFF_W3P);
    float* H1     = ws + OFF_H1E1;              // gate conv1 output (f32), dead after g2
    ushort_t* E1u = (ushort_t*)(ws + OFF_H1E1); // reuses H1 space (after g2 done)
    ushort_t* E2u = (ushort_t*)(ws + OFF_E2U);
    float* FINAL  = ws + OFF_FINAL;
    float* out    = (float*)d_out;

    init_kernel<<<512, 256, 0, stream>>>(SRWLOG, W2T, W2P, W3P, g_w2, ew2, ew3);
    fft_kernel<<<128, 256, 0, stream>>>(x, FFT);
    g1_kernel<<<dim3(9, 32, 128), 256, 0, stream>>>(FFT, g_w1, g_b1, H1);
    g2_kernel<<<dim3(33, 128), 256, 0, stream>>>(H1, W2T, g_b2, PART);
    mlp_kernel<<<128, 128, 0, stream>>>(PART, m_w1, m_b1, m_w2, m_b2, TW, TI, SRWLOG);
    aux_kernel<<<1, 64, 0, stream>>>(SRWLOG, out + 4194304);
    for (int k = 0; k < 2; ++k) {
        e1_kernel<<<dim3(5, 64, 128), 256, 0, stream>>>(FFT, ew1, eb1, TI, E1u, k);
        e2_kernel<<<dim3(9, 128), 256, 0, stream>>>(E1u, W2P, eb2, TI, E2u, k);
        e3_kernel<<<dim3(9, 128), 256, 0, stream>>>(E2u, W3P, eb3, TI, TW, FINAL, k);
    }
    maxpool_kernel<<<16384, 256, 0, stream>>>(FINAL, out);
}

// Round 4
// 462.880 us; speedup vs baseline: 2.1197x; 1.1140x over previous
//
#include <hip/hip_runtime.h>

#define NFREQ 2049
#define L1LEN 1025
#define L2LEN 513

typedef short v8s  __attribute__((ext_vector_type(8)));
typedef float v16f __attribute__((ext_vector_type(16)));
typedef unsigned short ushort_t;
typedef unsigned int uint_t;

// ---------------- workspace layout (float offsets) ----------------
#define OFF_FFT     0ull          // 524544
#define OFF_TWID    524544ull     // 2048
#define OFF_PTW     526592ull     // 4098 (+pad)
#define OFF_WIN     530944ull     // 4096
#define OFF_PART    535040ull     // 128*64*66 = 540672
#define OFF_TW      1075712ull    // 256
#define OFF_TI      1075968ull    // 256 (ints)
#define OFF_SRWLOG  1076224ull    // 16 (+pad 256)
#define OFF_W2H     1076480ull    // ushort 10240 -> 5120 fl
#define OFF_W2L     1081600ull    // 5120
#define OFF_EW2P    1086720ull    // ushort 327680 -> 163840
#define OFF_EW3P    1250560ull    // ushort 393216 -> 196608
#define OFF_H1P     1447168ull    // uint 128*2049*32 = 8392704
#define OFF_E1U     9839872ull    // ushort 8396800 -> 4198400
#define OFF_E2U     14038272ull   // ushort 8404992 -> 4202496
#define OFF_FINAL   18240768ull   // 8404992
// total 26,645,760 floats ~ 101.7 MiB

__device__ __forceinline__ float relu_f(float x) { return fmaxf(x, 0.0f); }
__device__ __forceinline__ int   rfl_i(int v)   { return __builtin_amdgcn_readfirstlane(v); }
__device__ __forceinline__ float rfl_f(float v) { return __uint_as_float((unsigned)__builtin_amdgcn_readfirstlane((int)__float_as_uint(v))); }
__device__ __forceinline__ ushort_t f2bf(float x) {
    unsigned u = __float_as_uint(x);
    unsigned r = (u + 0x7FFFu + ((u >> 16) & 1u)) >> 16;   // RNE
    return (ushort_t)r;
}
__device__ __forceinline__ float bf2f(ushort_t h) { return __uint_as_float(((unsigned)h) << 16); }

// ---------------- init: tables + zero aux + pack weights ----------------
__global__ void init_kernel(float* SRWLOG, float* TWID, float* PTW, float* WIN,
                            ushort_t* W2H, ushort_t* W2L, ushort_t* EW2P, ushort_t* EW3P,
                            const float* g_w2, const float* ew2, const float* ew3) {
    const float PI = 3.14159265358979323846f;
    int tid = blockIdx.x * blockDim.x + threadIdx.x;
    int stride = gridDim.x * blockDim.x;
    for (int i = tid; i < 16; i += stride) SRWLOG[i] = 0.0f;
    for (int j = tid; j < 1024; j += stride) {
        float a = PI * (float)j / 1024.0f;
        TWID[2 * j] = cosf(a);
        TWID[2 * j + 1] = -sinf(a);
    }
    for (int k = tid; k < 2049; k += stride) {
        float a = PI * (float)k / 2048.0f;
        PTW[2 * k] = cosf(a);
        PTW[2 * k + 1] = sinf(a);
    }
    for (int n = tid; n < 4096; n += stride) {
        WIN[n] = 0.5f * (1.0f - cosf(2.0f * PI * (float)n / 4096.0f));
    }
    // g_w2 (64,32,5) -> W2H/W2L[(t*64+o)*32 + c] split bf16
    for (int i = tid; i < 10240; i += stride) {
        int c = i & 31;
        int o = (i >> 5) & 63;
        int t = i >> 11;
        float w = g_w2[o * 160 + c * 5 + t];
        ushort_t h = f2bf(w);
        W2H[i] = h;
        W2L[i] = f2bf(w - bf2f(h));
    }
    // ew2 (8,128,64,5) -> EW2P[((e*5+t)*128+o)*64 + c] bf16
    for (int i = tid; i < 327680; i += stride) {
        int c = i & 63;
        int o = (i >> 6) & 127;
        int t = (i >> 13) % 5;
        int e = i / 40960;
        EW2P[i] = f2bf(ew2[((e * 128 + o) * 64 + c) * 5 + t]);
    }
    // ew3 (8,128,128,3) -> EW3P[((e*3+t)*128+o)*128 + c] bf16
    for (int i = tid; i < 393216; i += stride) {
        int c = i & 127;
        int o = (i >> 7) & 127;
        int t = (i >> 14) % 3;
        int e = i / 49152;
        EW3P[i] = f2bf(ew3[((e * 128 + o) * 128 + c) * 3 + t]);
    }
}

// ---------------- windowed rfft(4096) via 2048-pt complex FFT (table-driven) ----------------
__global__ __launch_bounds__(256) void fft_kernel(const float* __restrict__ x,
                                                  const float* __restrict__ TWID,
                                                  const float* __restrict__ PTW,
                                                  const float* __restrict__ WIN,
                                                  float* __restrict__ FFT) {
    __shared__ float re[2048];
    __shared__ float im[2048];
    int b = blockIdx.x, t = threadIdx.x;
    const float* xb = x + b * 4096;
    for (int i = t; i < 2048; i += 256) {
        int j = (int)(__brev((unsigned)i) >> 21);   // 11-bit reversal
        re[i] = xb[2 * j] * WIN[2 * j];
        im[i] = xb[2 * j + 1] * WIN[2 * j + 1];
    }
    for (int s = 1; s <= 11; ++s) {
        __syncthreads();
        int half = 1 << (s - 1);
        int shift = 11 - s;
        for (int bf = t; bf < 1024; bf += 256) {
            int grp = bf >> (s - 1);
            int pos = bf & (half - 1);
            int i1 = (grp << s) + pos;
            int i2 = i1 + half;
            int j = pos << shift;
            float wr = TWID[2 * j], wi = TWID[2 * j + 1];
            float ar = re[i2], ai = im[i2];
            float tr = wr * ar - wi * ai;
            float ti = wr * ai + wi * ar;
            float br = re[i1], bi = im[i1];
            re[i2] = br - tr; im[i2] = bi - ti;
            re[i1] = br + tr; im[i1] = bi + ti;
        }
    }
    __syncthreads();
    const float scale = 1.0f / 64.0f;
    for (int k = t; k <= 2048; k += 256) {
        int k1 = k & 2047;
        int k2 = (2048 - k) & 2047;
        float zr = re[k1], zi = im[k1];
        float yr = re[k2], yi = im[k2];
        float Er = 0.5f * (zr + yr), Ei = 0.5f * (zi - yi);
        float Or = 0.5f * (zi + yi), Oi = 0.5f * (yr - zr);
        float c2 = PTW[2 * k], s3 = PTW[2 * k + 1];
        FFT[b * 4098 + k]        = (Er + c2 * Or + s3 * Oi) * scale;
        FFT[b * 4098 + 2049 + k] = (Ei + c2 * Oi - s3 * Or) * scale;
    }
}

// ---------------- gate conv1 -> H1P packed (hi|lo) bf16, layout [b][pos][c] ----------------
// grid (9, 128), block 256: thread = one position, all 32 outputs
__global__ __launch_bounds__(256) void g1_kernel(const float* __restrict__ FFT,
                                                 const float* __restrict__ g_w1, const float* __restrict__ g_b1,
                                                 uint_t* __restrict__ H1P) {
    int pos = blockIdx.x * 256 + threadIdx.x;
    if (pos >= NFREQ) return;
    int b = blockIdx.y;
    const float* fb = FFT + b * 4098;
    float f[2][5];
    #pragma unroll
    for (int cc = 0; cc < 2; ++cc)
        #pragma unroll
        for (int tt = 0; tt < 5; ++tt) {
            int p = pos - 2 + tt;
            f[cc][tt] = (p >= 0 && p < NFREQ) ? fb[cc * NFREQ + p] : 0.0f;
        }
    uint_t* outp = H1P + (b * NFREQ + pos) * 32;
    #pragma unroll
    for (int o = 0; o < 32; ++o) {
        float a = g_b1[o];
        #pragma unroll
        for (int cc = 0; cc < 2; ++cc)
            #pragma unroll
            for (int tt = 0; tt < 5; ++tt)
                a = fmaf(f[cc][tt], g_w1[(o * 2 + cc) * 5 + tt], a);
        a = relu_f(a);
        ushort_t h = f2bf(a);
        ushort_t l = f2bf(a - bf2f(h));
        outp[o] = (uint_t)h | ((uint_t)l << 16);
    }
}

// ---------------- gate conv2 (split-precision MFMA) + partial mean-pool ----------------
// grid (33, 128); block 256 = 4 waves; wave w: o-tile (w&1)*32, q-half (w>>1)*32
__global__ __launch_bounds__(256) void g2_kernel(const uint_t* __restrict__ H1P,
                                                 const ushort_t* __restrict__ W2H, const ushort_t* __restrict__ W2L,
                                                 const float* __restrict__ g_b2,
                                                 float* __restrict__ PART) {
    __shared__ ushort_t xh[68][36];
    __shared__ ushort_t xl[68][36];
    int b = blockIdx.y;
    int q0 = blockIdx.x * 64;
    int t = threadIdx.x;
    for (int i = t; i < 68 * 32; i += 256) {
        int row = i >> 5, c = i & 31;
        int pos = q0 - 2 + row;
        uint_t v = (pos >= 0 && pos < NFREQ) ? H1P[(b * NFREQ + pos) * 32 + c] : 0u;
        xh[row][c] = (ushort_t)(v & 0xFFFFu);
        xl[row][c] = (ushort_t)(v >> 16);
    }
    __syncthreads();
    int lane = t & 63;
    int w = rfl_i(t >> 6);
    int tile_o = (w & 1) * 32;
    int qh = w >> 1;
    int n = lane & 31;
    int kg = lane >> 5;
    v16f acc;
    #pragma unroll
    for (int i = 0; i < 16; ++i) acc[i] = 0.0f;
    #pragma unroll
    for (int t5 = 0; t5 < 5; ++t5) {
        const ushort_t* whp = W2H + (t5 * 64 + tile_o + n) * 32;
        const ushort_t* wlp = W2L + (t5 * 64 + tile_o + n) * 32;
        int row = qh * 32 + n + t5;
        #pragma unroll
        for (int ks = 0; ks < 2; ++ks) {
            int c0 = ks * 16 + kg * 8;
            v8s Ah = *(const v8s*)(whp + c0);
            v8s Al = *(const v8s*)(wlp + c0);
            union { uint2 u[2]; v8s v; } Bh, Bl;
            const uint2* ph = (const uint2*)&xh[row][c0];
            const uint2* pl = (const uint2*)&xl[row][c0];
            Bh.u[0] = ph[0]; Bh.u[1] = ph[1];
            Bl.u[0] = pl[0]; Bl.u[1] = pl[1];
            acc = __builtin_amdgcn_mfma_f32_32x32x16_bf16(Ah, Bh.v, acc, 0, 0, 0);
            acc = __builtin_amdgcn_mfma_f32_32x32x16_bf16(Ah, Bl.v, acc, 0, 0, 0);
            acc = __builtin_amdgcn_mfma_f32_32x32x16_bf16(Al, Bh.v, acc, 0, 0, 0);
        }
    }
    int q = q0 + qh * 32 + n;
    bool valid = (q < NFREQ);
    #pragma unroll
    for (int r = 0; r < 16; ++r) {
        int m = (r & 3) + 8 * (r >> 2) + 4 * kg;
        int o = tile_o + m;
        float v = valid ? relu_f(acc[r] + g_b2[o]) : 0.0f;
        #pragma unroll
        for (int msk = 16; msk >= 1; msk >>= 1) v += __shfl_xor(v, msk, 64);
        if (n == 0) PART[(b * 64 + o) * 66 + blockIdx.x * 2 + qh] = v;
    }
}

// ---------------- router MLP + softmax + top2 + aux partials ----------------
__global__ __launch_bounds__(128) void mlp_kernel(const float* __restrict__ PART,
                                                  const float* __restrict__ m_w1, const float* __restrict__ m_b1,
                                                  const float* __restrict__ m_w2, const float* __restrict__ m_b2,
                                                  float* TW, int* TI, float* SRWLOG) {
    __shared__ float pooledS[64];
    __shared__ float hid[128];
    __shared__ float lgS[8];
    __shared__ float rwS[8];
    int b = blockIdx.x, t = threadIdx.x;
    if (t < 64) {
        float s = 0.0f;
        const float* pp = PART + (b * 64 + t) * 66;
        for (int blk = 0; blk < 66; ++blk) s += pp[blk];
        pooledS[t] = s;
    }
    __syncthreads();
    const float inv = 1.0f / 2049.0f;
    {
        float h = m_b1[t];
        for (int c = 0; c < 64; ++c)
            h = fmaf(pooledS[c] * inv, m_w1[t * 64 + c], h);
        hid[t] = relu_f(h);
    }
    __syncthreads();
    if (t < 8) {
        float lg = m_b2[t];
        for (int j = 0; j < 128; ++j) lg = fmaf(hid[j], m_w2[t * 128 + j], lg);
        lgS[t] = lg;
    }
    __syncthreads();
    if (t == 0) {
        float mx = lgS[0];
        for (int e = 1; e < 8; ++e) mx = fmaxf(mx, lgS[e]);
        float s = 0.0f, ex[8];
        for (int e = 0; e < 8; ++e) { ex[e] = expf(lgS[e] - mx); s += ex[e]; }
        for (int e = 0; e < 8; ++e) rwS[e] = ex[e] / s;
        int i1 = 0;
        for (int e = 1; e < 8; ++e) if (rwS[e] > rwS[i1]) i1 = e;
        int i2 = (i1 == 0) ? 1 : 0;
        for (int e = 0; e < 8; ++e) if (e != i1 && rwS[e] > rwS[i2]) i2 = e;
        float t0 = rwS[i1], t1 = rwS[i2], sm = t0 + t1;
        TW[b * 2] = t0 / sm; TW[b * 2 + 1] = t1 / sm;
        TI[b * 2] = i1; TI[b * 2 + 1] = i2;
    }
    __syncthreads();
    if (t < 8) {
        atomicAdd(&SRWLOG[t], rwS[t]);
        atomicAdd(&SRWLOG[8 + t], lgS[t]);
    }
}

__global__ void aux_kernel(const float* SRWLOG, float* out_aux) {
    if (threadIdx.x == 0 && blockIdx.x == 0) {
        float a = 0.0f;
        for (int e = 0; e < 8; ++e)
            a += (SRWLOG[e] / 128.0f) * (SRWLOG[8 + e] / 128.0f);
        out_aux[0] = 0.01f * 8.0f * a;
    }
}

// ---------------- expert conv1: (2->64, k=7, s=2, p=3), bf16 out ----------------
__global__ __launch_bounds__(256) void e1_kernel(const float* __restrict__ FFT,
                                                 const float* __restrict__ ew1, const float* __restrict__ eb1,
                                                 const int* __restrict__ TI, ushort_t* __restrict__ E1u, int k) {
    int r = blockIdx.x * 256 + threadIdx.x;
    if (r >= L1LEN) return;
    int o = blockIdx.y;
    int b = blockIdx.z;
    int e = rfl_i(TI[b * 2 + k]);
    const float* fb = FFT + b * 4098;
    const float* w = ew1 + (e * 64 + o) * 14;
    float a = eb1[e * 64 + o];
    #pragma unroll
    for (int c = 0; c < 2; ++c)
        #pragma unroll
        for (int tt = 0; tt < 7; ++tt) {
            int pos = 2 * r - 3 + tt;
            if (pos >= 0 && pos < NFREQ)
                a = fmaf(fb[c * NFREQ + pos], w[c * 7 + tt], a);
        }
    E1u[(b * 64 + o) * L1LEN + r] = f2bf(relu_f(a));
}

// ---------------- expert conv2 (MFMA): (64->128, k=5, s=2, p=2) ----------------
__global__ __launch_bounds__(256) void e2_kernel(const ushort_t* __restrict__ E1u,
                                                 const ushort_t* __restrict__ EW2P, const float* __restrict__ eb2,
                                                 const int* __restrict__ TI, ushort_t* __restrict__ E2u, int k) {
    __shared__ ushort_t xe[66][68];
    __shared__ ushort_t xo[66][68];
    int b = blockIdx.y;
    int q0 = blockIdx.x * 64;
    int t = threadIdx.x;
    int e = rfl_i(TI[b * 2 + k]);
    for (int i = t; i < 64 * 132; i += 256) {
        int c = i / 132, poff = i % 132;
        int pos = 2 * q0 - 2 + poff;
        ushort_t v = (pos >= 0 && pos < L1LEN) ? E1u[(b * 64 + c) * L1LEN + pos] : (ushort_t)0;
        int row = poff >> 1;
        if (poff & 1) xo[row][c] = v; else xe[row][c] = v;
    }
    __syncthreads();
    int lane = t & 63;
    int w = rfl_i(t >> 6);
    int n = lane & 31;
    int kg = lane >> 5;
    v16f acc0, acc1;
    #pragma unroll
    for (int i = 0; i < 16; ++i) { acc0[i] = 0.0f; acc1[i] = 0.0f; }
    #pragma unroll
    for (int t5 = 0; t5 < 5; ++t5) {
        const ushort_t* wrow = EW2P + (((e * 5 + t5) * 128) + w * 32 + n) * 64;
        int roff = t5 >> 1;
        const ushort_t (*sel)[68] = (t5 & 1) ? xo : xe;
        #pragma unroll
        for (int ks = 0; ks < 4; ++ks) {
            int c0 = ks * 16 + kg * 8;
            v8s a = *(const v8s*)(wrow + c0);
            union { uint2 u[2]; v8s v; } b0u, b1u;
            const uint2* p0 = (const uint2*)&sel[n + roff][c0];
            const uint2* p1 = (const uint2*)&sel[n + 32 + roff][c0];
            b0u.u[0] = p0[0]; b0u.u[1] = p0[1];
            b1u.u[0] = p1[0]; b1u.u[1] = p1[1];
            acc0 = __builtin_amdgcn_mfma_f32_32x32x16_bf16(a, b0u.v, acc0, 0, 0, 0);
            acc1 = __builtin_amdgcn_mfma_f32_32x32x16_bf16(a, b1u.v, acc1, 0, 0, 0);
        }
    }
    #pragma unroll
    for (int r = 0; r < 16; ++r) {
        int m = (r & 3) + 8 * (r >> 2) + 4 * kg;
        int o = w * 32 + m;
        float bias = eb2[e * 128 + o];
        int q = q0 + n;
        if (q < L2LEN)      E2u[(b * 128 + o) * L2LEN + q]  = f2bf(relu_f(acc0[r] + bias));
        int q2 = q0 + 32 + n;
        if (q2 < L2LEN)     E2u[(b * 128 + o) * L2LEN + q2] = f2bf(relu_f(acc1[r] + bias));
    }
}

// ---------------- expert conv3 (MFMA) + weighted accumulate ----------------
__global__ __launch_bounds__(256) void e3_kernel(const ushort_t* __restrict__ E2u,
                                                 const ushort_t* __restrict__ EW3P, const float* __restrict__ eb3,
                                                 const int* __restrict__ TI, const float* __restrict__ TW,
                                                 float* __restrict__ FINAL, int k) {
    __shared__ ushort_t xT[66][132];
    int b = blockIdx.y;
    int q0 = blockIdx.x * 64;
    int t = threadIdx.x;
    int e = rfl_i(TI[b * 2 + k]);
    float wk = rfl_f(TW[b * 2 + k]);
    for (int i = t; i < 128 * 66; i += 256) {
        int c = i / 66, row = i % 66;
        int pos = q0 - 1 + row;
        xT[row][c] = (pos >= 0 && pos < L2LEN) ? E2u[(b * 128 + c) * L2LEN + pos] : (ushort_t)0;
    }
    __syncthreads();
    int lane = t & 63;
    int w = rfl_i(t >> 6);
    int n = lane & 31;
    int kg = lane >> 5;
    v16f acc0, acc1;
    #pragma unroll
    for (int i = 0; i < 16; ++i) { acc0[i] = 0.0f; acc1[i] = 0.0f; }
    #pragma unroll
    for (int t3 = 0; t3 < 3; ++t3) {
        const ushort_t* wrow = EW3P + (((e * 3 + t3) * 128) + w * 32 + n) * 128;
        #pragma unroll
        for (int ks = 0; ks < 8; ++ks) {
            int c0 = ks * 16 + kg * 8;
            v8s a = *(const v8s*)(wrow + c0);
            union { uint2 u[2]; v8s v; } b0u, b1u;
            const uint2* p0 = (const uint2*)&xT[n + t3][c0];
            const uint2* p1 = (const uint2*)&xT[n + 32 + t3][c0];
            b0u.u[0] = p0[0]; b0u.u[1] = p0[1];
            b1u.u[0] = p1[0]; b1u.u[1] = p1[1];
            acc0 = __builtin_amdgcn_mfma_f32_32x32x16_bf16(a, b0u.v, acc0, 0, 0, 0);
            acc1 = __builtin_amdgcn_mfma_f32_32x32x16_bf16(a, b1u.v, acc1, 0, 0, 0);
        }
    }
    #pragma unroll
    for (int r = 0; r < 16; ++r) {
        int m = (r & 3) + 8 * (r >> 2) + 4 * kg;
        int o = w * 32 + m;
        float bias = eb3[e * 128 + o];
        int q = q0 + n;
        if (q < L2LEN) {
            float v = relu_f(acc0[r] + bias) * wk;
            int oi = (b * 128 + o) * L2LEN + q;
            if (k == 0) FINAL[oi] = v; else FINAL[oi] += v;
        }
        int q2 = q0 + 32 + n;
        if (q2 < L2LEN) {
            float v = relu_f(acc1[r] + bias) * wk;
            int oi = (b * 128 + o) * L2LEN + q2;
            if (k == 0) FINAL[oi] = v; else FINAL[oi] += v;
        }
    }
}

// ---------------- adaptive max-pool 513 -> 256 ----------------
__global__ __launch_bounds__(256) void maxpool_kernel(const float* __restrict__ FINAL, float* __restrict__ out) {
    int idx = blockIdx.x * 256 + threadIdx.x;
    if (idx >= 128 * 128 * 256) return;
    int j = idx & 255;
    int bo = idx >> 8;
    int s = (j * 513) >> 8;
    int e_ = (j * 513 + 768) >> 8;
    const float* f = FINAL + bo * L2LEN;
    float m = f[s];
    if (s + 1 < e_) m = fmaxf(m, f[s + 1]);
    if (s + 2 < e_) m = fmaxf(m, f[s + 2]);
    out[idx] = m;
}

extern "C" void kernel_launch(void* const* d_in, const int* in_sizes, int n_in,
                              void* d_out, int out_size, void* d_ws, size_t ws_size,
                              hipStream_t stream) {
    const float* x    = (const float*)d_in[0];
    const float* g_w1 = (const float*)d_in[1];
    const float* g_b1 = (const float*)d_in[2];
    const float* g_w2 = (const float*)d_in[3];
    const float* g_b2 = (const float*)d_in[4];
    const float* m_w1 = (const float*)d_in[5];
    const float* m_b1 = (const float*)d_in[6];
    const float* m_w2 = (const float*)d_in[7];
    const float* m_b2 = (const float*)d_in[8];
    const float* ew1  = (const float*)d_in[9];
    const float* eb1  = (const float*)d_in[10];
    const float* ew2  = (const float*)d_in[11];
    const float* eb2  = (const float*)d_in[12];
    const float* ew3  = (const float*)d_in[13];
    const float* eb3  = (const float*)d_in[14];

    float* ws     = (float*)d_ws;
    float* FFT    = ws + OFF_FFT;
    float* TWID   = ws + OFF_TWID;
    float* PTW    = ws + OFF_PTW;
    float* WIN    = ws + OFF_WIN;
    float* PART   = ws + OFF_PART;
    float* TW     = ws + OFF_TW;
    int*   TI     = (int*)(ws + OFF_TI);
    float* SRWLOG = ws + OFF_SRWLOG;
    ushort_t* W2H = (ushort_t*)(ws + OFF_W2H);
    ushort_t* W2L = (ushort_t*)(ws + OFF_W2L);
    ushort_t* EW2P = (ushort_t*)(ws + OFF_EW2P);
    ushort_t* EW3P = (ushort_t*)(ws + OFF_EW3P);
    uint_t* H1P   = (uint_t*)(ws + OFF_H1P);
    ushort_t* E1u = (ushort_t*)(ws + OFF_E1U);
    ushort_t* E2u = (ushort_t*)(ws + OFF_E2U);
    float* FINAL  = ws + OFF_FINAL;
    float* out    = (float*)d_out;

    init_kernel<<<512, 256, 0, stream>>>(SRWLOG, TWID, PTW, WIN, W2H, W2L, EW2P, EW3P, g_w2, ew2, ew3);
    fft_kernel<<<128, 256, 0, stream>>>(x, TWID, PTW, WIN, FFT);
    g1_kernel<<<dim3(9, 128), 256, 0, stream>>>(FFT, g_w1, g_b1, H1P);
    g2_kernel<<<dim3(33, 128), 256, 0, stream>>>(H1P, W2H, W2L, g_b2, PART);
    mlp_kernel<<<128, 128, 0, stream>>>(PART, m_w1, m_b1, m_w2, m_b2, TW, TI, SRWLOG);
    aux_kernel<<<1, 64, 0, stream>>>(SRWLOG, out + 4194304);
    for (int k = 0; k < 2; ++k) {
        e1_kernel<<<dim3(5, 64, 128), 256, 0, stream>>>(FFT, ew1, eb1, TI, E1u, k);
        e2_kernel<<<dim3(9, 128), 256, 0, stream>>>(E1u, EW2P, eb2, TI, E2u, k);
        e3_kernel<<<dim3(9, 128), 256, 0, stream>>>(E2u, EW3P, eb3, TI, TW, FINAL, k);
    }
    maxpool_kernel<<<16384, 256, 0, stream>>>(FINAL, out);
}

// Round 5
// 391.306 us; speedup vs baseline: 2.5074x; 1.1829x over previous
//
#include <hip/hip_runtime.h>

#define NFREQ 2049
#define L1LEN 1025
#define L2LEN 513

typedef short v8s  __attribute__((ext_vector_type(8)));
typedef float v16f __attribute__((ext_vector_type(16)));
typedef unsigned short ushort_t;
typedef unsigned int uint_t;

// ---------------- workspace layout (float offsets) ----------------
#define OFF_FFT     0ull          // 524544
#define OFF_TWID    524544ull     // 2048
#define OFF_PTW     526592ull     // 4352 (4098 + pad)
#define OFF_WIN     530944ull     // 4096
#define OFF_PART    535040ull     // 540672
#define OFF_TW      1075712ull    // 256
#define OFF_TI      1075968ull    // 256 (ints)
#define OFF_SRWLOG  1076224ull    // 256
#define OFF_W2H     1076480ull    // 5120
#define OFF_W2L     1081600ull    // 5120
#define OFF_EW2P    1086720ull    // 163840 (ushort 327680)
#define OFF_EW3P    1250560ull    // 196608 (ushort 393216)
#define OFF_A       1447168ull    // 8396800: H1P (uint 8392704), then E1u[2] (ushort 2*8396800)
#define OFF_E2U     9843968ull    // 8404992: E2u[2] (ushort 2*8404992)
#define OFF_FINAL   18248960ull   // 8404992 (f32, atomically accumulated)
// total 26,653,952 floats ~ 101.7 MiB (<= round-1 proven 26,733,328)

#define E1U_K_STRIDE 8396800      // ushort elements per k
#define E2U_K_STRIDE 8404992      // ushort elements per k

__device__ __forceinline__ float relu_f(float x) { return fmaxf(x, 0.0f); }
__device__ __forceinline__ int   rfl_i(int v)   { return __builtin_amdgcn_readfirstlane(v); }
__device__ __forceinline__ float rfl_f(float v) { return __uint_as_float((unsigned)__builtin_amdgcn_readfirstlane((int)__float_as_uint(v))); }
__device__ __forceinline__ ushort_t f2bf(float x) {
    unsigned u = __float_as_uint(x);
    unsigned r = (u + 0x7FFFu + ((u >> 16) & 1u)) >> 16;   // RNE
    return (ushort_t)r;
}
__device__ __forceinline__ float bf2f(ushort_t h) { return __uint_as_float(((unsigned)h) << 16); }

// ---------------- init: tables + zero aux/FINAL + pack weights ----------------
__global__ void init_kernel(float* SRWLOG, float* TWID, float* PTW, float* WIN,
                            ushort_t* W2H, ushort_t* W2L, ushort_t* EW2P, ushort_t* EW3P,
                            float* FINAL,
                            const float* g_w2, const float* ew2, const float* ew3) {
    const float PI = 3.14159265358979323846f;
    int tid = blockIdx.x * blockDim.x + threadIdx.x;
    int stride = gridDim.x * blockDim.x;
    for (int i = tid; i < 16; i += stride) SRWLOG[i] = 0.0f;
    for (int i = tid; i < 8404992; i += stride) FINAL[i] = 0.0f;
    for (int j = tid; j < 1024; j += stride) {
        float a = PI * (float)j / 1024.0f;
        TWID[2 * j] = cosf(a);
        TWID[2 * j + 1] = -sinf(a);
    }
    for (int k = tid; k < 2049; k += stride) {
        float a = PI * (float)k / 2048.0f;
        PTW[2 * k] = cosf(a);
        PTW[2 * k + 1] = sinf(a);
    }
    for (int n = tid; n < 4096; n += stride) {
        WIN[n] = 0.5f * (1.0f - cosf(2.0f * PI * (float)n / 4096.0f));
    }
    // g_w2 (64,32,5) -> W2H/W2L[(t*64+o)*32 + c] split bf16
    for (int i = tid; i < 10240; i += stride) {
        int c = i & 31;
        int o = (i >> 5) & 63;
        int t = i >> 11;
        float w = g_w2[o * 160 + c * 5 + t];
        ushort_t h = f2bf(w);
        W2H[i] = h;
        W2L[i] = f2bf(w - bf2f(h));
    }
    // ew2 (8,128,64,5) -> EW2P[((e*5+t)*128+o)*64 + c] bf16
    for (int i = tid; i < 327680; i += stride) {
        int c = i & 63;
        int o = (i >> 6) & 127;
        int t = (i >> 13) % 5;
        int e = i / 40960;
        EW2P[i] = f2bf(ew2[((e * 128 + o) * 64 + c) * 5 + t]);
    }
    // ew3 (8,128,128,3) -> EW3P[((e*3+t)*128+o)*128 + c] bf16
    for (int i = tid; i < 393216; i += stride) {
        int c = i & 127;
        int o = (i >> 7) & 127;
        int t = (i >> 14) % 3;
        int e = i / 49152;
        EW3P[i] = f2bf(ew3[((e * 128 + o) * 128 + c) * 3 + t]);
    }
}

// ---------------- windowed rfft(4096) via 2048-pt complex FFT (table-driven) ----------------
__global__ __launch_bounds__(256) void fft_kernel(const float* __restrict__ x,
                                                  const float* __restrict__ TWID,
                                                  const float* __restrict__ PTW,
                                                  const float* __restrict__ WIN,
                                                  float* __restrict__ FFT) {
    __shared__ float re[2048];
    __shared__ float im[2048];
    int b = blockIdx.x, t = threadIdx.x;
    const float* xb = x + b * 4096;
    for (int i = t; i < 2048; i += 256) {
        int j = (int)(__brev((unsigned)i) >> 21);   // 11-bit reversal
        re[i] = xb[2 * j] * WIN[2 * j];
        im[i] = xb[2 * j + 1] * WIN[2 * j + 1];
    }
    for (int s = 1; s <= 11; ++s) {
        __syncthreads();
        int half = 1 << (s - 1);
        int shift = 11 - s;
        for (int bf = t; bf < 1024; bf += 256) {
            int grp = bf >> (s - 1);
            int pos = bf & (half - 1);
            int i1 = (grp << s) + pos;
            int i2 = i1 + half;
            int j = pos << shift;
            float wr = TWID[2 * j], wi = TWID[2 * j + 1];
            float ar = re[i2], ai = im[i2];
            float tr = wr * ar - wi * ai;
            float ti = wr * ai + wi * ar;
            float br = re[i1], bi = im[i1];
            re[i2] = br - tr; im[i2] = bi - ti;
            re[i1] = br + tr; im[i1] = bi + ti;
        }
    }
    __syncthreads();
    const float scale = 1.0f / 64.0f;
    for (int k = t; k <= 2048; k += 256) {
        int k1 = k & 2047;
        int k2 = (2048 - k) & 2047;
        float zr = re[k1], zi = im[k1];
        float yr = re[k2], yi = im[k2];
        float Er = 0.5f * (zr + yr), Ei = 0.5f * (zi - yi);
        float Or = 0.5f * (zi + yi), Oi = 0.5f * (yr - zr);
        float c2 = PTW[2 * k], s3 = PTW[2 * k + 1];
        FFT[b * 4098 + k]        = (Er + c2 * Or + s3 * Oi) * scale;
        FFT[b * 4098 + 2049 + k] = (Ei + c2 * Oi - s3 * Or) * scale;
    }
}

// ---------------- gate conv1 -> H1P packed (hi|lo) bf16, layout [b][pos][c] ----------------
__global__ __launch_bounds__(256) void g1_kernel(const float* __restrict__ FFT,
                                                 const float* __restrict__ g_w1, const float* __restrict__ g_b1,
                                                 uint_t* __restrict__ H1P) {
    int pos = blockIdx.x * 256 + threadIdx.x;
    if (pos >= NFREQ) return;
    int b = blockIdx.y;
    const float* fb = FFT + b * 4098;
    float f[2][5];
    #pragma unroll
    for (int cc = 0; cc < 2; ++cc)
        #pragma unroll
        for (int tt = 0; tt < 5; ++tt) {
            int p = pos - 2 + tt;
            f[cc][tt] = (p >= 0 && p < NFREQ) ? fb[cc * NFREQ + p] : 0.0f;
        }
    uint_t* outp = H1P + (b * NFREQ + pos) * 32;
    #pragma unroll
    for (int o = 0; o < 32; ++o) {
        float a = g_b1[o];
        #pragma unroll
        for (int cc = 0; cc < 2; ++cc)
            #pragma unroll
            for (int tt = 0; tt < 5; ++tt)
                a = fmaf(f[cc][tt], g_w1[(o * 2 + cc) * 5 + tt], a);
        a = relu_f(a);
        ushort_t h = f2bf(a);
        ushort_t l = f2bf(a - bf2f(h));
        outp[o] = (uint_t)h | ((uint_t)l << 16);
    }
}

// ---------------- gate conv2 (split-precision MFMA) + partial mean-pool ----------------
__global__ __launch_bounds__(256) void g2_kernel(const uint_t* __restrict__ H1P,
                                                 const ushort_t* __restrict__ W2H, const ushort_t* __restrict__ W2L,
                                                 const float* __restrict__ g_b2,
                                                 float* __restrict__ PART) {
    __shared__ ushort_t xh[68][36];
    __shared__ ushort_t xl[68][36];
    int b = blockIdx.y;
    int q0 = blockIdx.x * 64;
    int t = threadIdx.x;
    for (int i = t; i < 68 * 32; i += 256) {
        int row = i >> 5, c = i & 31;
        int pos = q0 - 2 + row;
        uint_t v = (pos >= 0 && pos < NFREQ) ? H1P[(b * NFREQ + pos) * 32 + c] : 0u;
        xh[row][c] = (ushort_t)(v & 0xFFFFu);
        xl[row][c] = (ushort_t)(v >> 16);
    }
    __syncthreads();
    int lane = t & 63;
    int w = rfl_i(t >> 6);
    int tile_o = (w & 1) * 32;
    int qh = w >> 1;
    int n = lane & 31;
    int kg = lane >> 5;
    v16f acc;
    #pragma unroll
    for (int i = 0; i < 16; ++i) acc[i] = 0.0f;
    #pragma unroll
    for (int t5 = 0; t5 < 5; ++t5) {
        const ushort_t* whp = W2H + (t5 * 64 + tile_o + n) * 32;
        const ushort_t* wlp = W2L + (t5 * 64 + tile_o + n) * 32;
        int row = qh * 32 + n + t5;
        #pragma unroll
        for (int ks = 0; ks < 2; ++ks) {
            int c0 = ks * 16 + kg * 8;
            v8s Ah = *(const v8s*)(whp + c0);
            v8s Al = *(const v8s*)(wlp + c0);
            union { uint2 u[2]; v8s v; } Bh, Bl;
            const uint2* ph = (const uint2*)&xh[row][c0];
            const uint2* pl = (const uint2*)&xl[row][c0];
            Bh.u[0] = ph[0]; Bh.u[1] = ph[1];
            Bl.u[0] = pl[0]; Bl.u[1] = pl[1];
            acc = __builtin_amdgcn_mfma_f32_32x32x16_bf16(Ah, Bh.v, acc, 0, 0, 0);
            acc = __builtin_amdgcn_mfma_f32_32x32x16_bf16(Ah, Bl.v, acc, 0, 0, 0);
            acc = __builtin_amdgcn_mfma_f32_32x32x16_bf16(Al, Bh.v, acc, 0, 0, 0);
        }
    }
    int q = q0 + qh * 32 + n;
    bool valid = (q < NFREQ);
    #pragma unroll
    for (int r = 0; r < 16; ++r) {
        int m = (r & 3) + 8 * (r >> 2) + 4 * kg;
        int o = tile_o + m;
        float v = valid ? relu_f(acc[r] + g_b2[o]) : 0.0f;
        #pragma unroll
        for (int msk = 16; msk >= 1; msk >>= 1) v += __shfl_xor(v, msk, 64);
        if (n == 0) PART[(b * 64 + o) * 66 + blockIdx.x * 2 + qh] = v;
    }
}

// ---------------- router MLP + softmax + top2 + aux partials ----------------
__global__ __launch_bounds__(128) void mlp_kernel(const float* __restrict__ PART,
                                                  const float* __restrict__ m_w1, const float* __restrict__ m_b1,
                                                  const float* __restrict__ m_w2, const float* __restrict__ m_b2,
                                                  float* TW, int* TI, float* SRWLOG) {
    __shared__ float pooledS[64];
    __shared__ float hid[128];
    __shared__ float lgS[8];
    __shared__ float rwS[8];
    int b = blockIdx.x, t = threadIdx.x;
    if (t < 64) {
        float s = 0.0f;
        const float* pp = PART + (b * 64 + t) * 66;
        for (int blk = 0; blk < 66; ++blk) s += pp[blk];
        pooledS[t] = s;
    }
    __syncthreads();
    const float inv = 1.0f / 2049.0f;
    {
        float h = m_b1[t];
        for (int c = 0; c < 64; ++c)
            h = fmaf(pooledS[c] * inv, m_w1[t * 64 + c], h);
        hid[t] = relu_f(h);
    }
    __syncthreads();
    if (t < 8) {
        float lg = m_b2[t];
        for (int j = 0; j < 128; ++j) lg = fmaf(hid[j], m_w2[t * 128 + j], lg);
        lgS[t] = lg;
    }
    __syncthreads();
    if (t == 0) {
        float mx = lgS[0];
        for (int e = 1; e < 8; ++e) mx = fmaxf(mx, lgS[e]);
        float s = 0.0f, ex[8];
        for (int e = 0; e < 8; ++e) { ex[e] = expf(lgS[e] - mx); s += ex[e]; }
        for (int e = 0; e < 8; ++e) rwS[e] = ex[e] / s;
        int i1 = 0;
        for (int e = 1; e < 8; ++e) if (rwS[e] > rwS[i1]) i1 = e;
        int i2 = (i1 == 0) ? 1 : 0;
        for (int e = 0; e < 8; ++e) if (e != i1 && rwS[e] > rwS[i2]) i2 = e;
        float t0 = rwS[i1], t1 = rwS[i2], sm = t0 + t1;
        TW[b * 2] = t0 / sm; TW[b * 2 + 1] = t1 / sm;
        TI[b * 2] = i1; TI[b * 2 + 1] = i2;
    }
    __syncthreads();
    if (t < 8) {
        atomicAdd(&SRWLOG[t], rwS[t]);
        atomicAdd(&SRWLOG[8 + t], lgS[t]);
    }
}

__global__ void aux_kernel(const float* SRWLOG, float* out_aux) {
    if (threadIdx.x == 0 && blockIdx.x == 0) {
        float a = 0.0f;
        for (int e = 0; e < 8; ++e)
            a += (SRWLOG[e] / 128.0f) * (SRWLOG[8 + e] / 128.0f);
        out_aux[0] = 0.01f * 8.0f * a;
    }
}

// ---------------- expert conv1: (2->64, k=7, s=2, p=3), bf16 out ----------------
// grid (5, 128, 2): block = 256 positions x ALL 64 outputs; FFT tile in LDS;
// weights stay scalar (uniform e), 896 fma/thread.
__global__ __launch_bounds__(256) void e1_kernel(const float* __restrict__ FFT,
                                                 const float* __restrict__ ew1, const float* __restrict__ eb1,
                                                 const int* __restrict__ TI, ushort_t* __restrict__ E1u) {
    __shared__ float xs[2][520];
    int r0 = blockIdx.x * 256;
    int b = blockIdx.y;
    int k = blockIdx.z;
    int t = threadIdx.x;
    int e = rfl_i(TI[b * 2 + k]);
    int lo = 2 * r0 - 3;
    const float* fb = FFT + b * 4098;
    for (int i = t; i < 2 * 520; i += 256) {
        int ch = i / 520, off = i % 520;
        int pos = lo + off;
        xs[ch][off] = (pos >= 0 && pos < NFREQ) ? fb[ch * NFREQ + pos] : 0.0f;
    }
    __syncthreads();
    int r = r0 + t;
    if (r >= L1LEN) return;
    float xv[14];
    #pragma unroll
    for (int ch = 0; ch < 2; ++ch)
        #pragma unroll
        for (int tt = 0; tt < 7; ++tt)
            xv[ch * 7 + tt] = xs[ch][2 * t + tt];
    const float* wb = ew1 + e * 64 * 14;
    const float* bb = eb1 + e * 64;
    ushort_t* outb = E1u + (size_t)k * E1U_K_STRIDE + (size_t)b * 64 * L1LEN + r;
    for (int o = 0; o < 64; ++o) {
        float a = bb[o];
        const float* w = wb + o * 14;
        #pragma unroll
        for (int j = 0; j < 14; ++j)
            a = fmaf(xv[j], w[j], a);
        outb[o * L1LEN] = f2bf(relu_f(a));
    }
}

// ---------------- expert conv2 (MFMA): (64->128, k=5, s=2, p=2) ----------------
// grid (9, 128, 2)
__global__ __launch_bounds__(256) void e2_kernel(const ushort_t* __restrict__ E1u,
                                                 const ushort_t* __restrict__ EW2P, const float* __restrict__ eb2,
                                                 const int* __restrict__ TI, ushort_t* __restrict__ E2u) {
    __shared__ ushort_t xe[66][68];
    __shared__ ushort_t xo[66][68];
    int b = blockIdx.y;
    int k = blockIdx.z;
    int q0 = blockIdx.x * 64;
    int t = threadIdx.x;
    int e = rfl_i(TI[b * 2 + k]);
    const ushort_t* E1k = E1u + (size_t)k * E1U_K_STRIDE;
    for (int i = t; i < 64 * 132; i += 256) {
        int c = i / 132, poff = i % 132;
        int pos = 2 * q0 - 2 + poff;
        ushort_t v = (pos >= 0 && pos < L1LEN) ? E1k[(b * 64 + c) * L1LEN + pos] : (ushort_t)0;
        int row = poff >> 1;
        if (poff & 1) xo[row][c] = v; else xe[row][c] = v;
    }
    __syncthreads();
    int lane = t & 63;
    int w = rfl_i(t >> 6);
    int n = lane & 31;
    int kg = lane >> 5;
    v16f acc0, acc1;
    #pragma unroll
    for (int i = 0; i < 16; ++i) { acc0[i] = 0.0f; acc1[i] = 0.0f; }
    #pragma unroll
    for (int t5 = 0; t5 < 5; ++t5) {
        const ushort_t* wrow = EW2P + (((e * 5 + t5) * 128) + w * 32 + n) * 64;
        int roff = t5 >> 1;
        const ushort_t (*sel)[68] = (t5 & 1) ? xo : xe;
        #pragma unroll
        for (int ks = 0; ks < 4; ++ks) {
            int c0 = ks * 16 + kg * 8;
            v8s a = *(const v8s*)(wrow + c0);
            union { uint2 u[2]; v8s v; } b0u, b1u;
            const uint2* p0 = (const uint2*)&sel[n + roff][c0];
            const uint2* p1 = (const uint2*)&sel[n + 32 + roff][c0];
            b0u.u[0] = p0[0]; b0u.u[1] = p0[1];
            b1u.u[0] = p1[0]; b1u.u[1] = p1[1];
            acc0 = __builtin_amdgcn_mfma_f32_32x32x16_bf16(a, b0u.v, acc0, 0, 0, 0);
            acc1 = __builtin_amdgcn_mfma_f32_32x32x16_bf16(a, b1u.v, acc1, 0, 0, 0);
        }
    }
    ushort_t* E2k = E2u + (size_t)k * E2U_K_STRIDE;
    #pragma unroll
    for (int r = 0; r < 16; ++r) {
        int m = (r & 3) + 8 * (r >> 2) + 4 * kg;
        int o = w * 32 + m;
        float bias = eb2[e * 128 + o];
        int q = q0 + n;
        if (q < L2LEN)      E2k[(b * 128 + o) * L2LEN + q]  = f2bf(relu_f(acc0[r] + bias));
        int q2 = q0 + 32 + n;
        if (q2 < L2LEN)     E2k[(b * 128 + o) * L2LEN + q2] = f2bf(relu_f(acc1[r] + bias));
    }
}

// ---------------- expert conv3 (MFMA) + weighted atomic accumulate ----------------
// grid (9, 128, 2); FINAL pre-zeroed by init_kernel
__global__ __launch_bounds__(256) void e3_kernel(const ushort_t* __restrict__ E2u,
                                                 const ushort_t* __restrict__ EW3P, const float* __restrict__ eb3,
                                                 const int* __restrict__ TI, const float* __restrict__ TW,
                                                 float* __restrict__ FINAL) {
    __shared__ ushort_t xT[66][132];
    int b = blockIdx.y;
    int k = blockIdx.z;
    int q0 = blockIdx.x * 64;
    int t = threadIdx.x;
    int e = rfl_i(TI[b * 2 + k]);
    float wk = rfl_f(TW[b * 2 + k]);
    const ushort_t* E2k = E2u + (size_t)k * E2U_K_STRIDE;
    for (int i = t; i < 128 * 66; i += 256) {
        int c = i / 66, row = i % 66;
        int pos = q0 - 1 + row;
        xT[row][c] = (pos >= 0 && pos < L2LEN) ? E2k[(b * 128 + c) * L2LEN + pos] : (ushort_t)0;
    }
    __syncthreads();
    int lane = t & 63;
    int w = rfl_i(t >> 6);
    int n = lane & 31;
    int kg = lane >> 5;
    v16f acc0, acc1;
    #pragma unroll
    for (int i = 0; i < 16; ++i) { acc0[i] = 0.0f; acc1[i] = 0.0f; }
    #pragma unroll
    for (int t3 = 0; t3 < 3; ++t3) {
        const ushort_t* wrow = EW3P + (((e * 3 + t3) * 128) + w * 32 + n) * 128;
        #pragma unroll
        for (int ks = 0; ks < 8; ++ks) {
            int c0 = ks * 16 + kg * 8;
            v8s a = *(const v8s*)(wrow + c0);
            union { uint2 u[2]; v8s v; } b0u, b1u;
            const uint2* p0 = (const uint2*)&xT[n + t3][c0];
            const uint2* p1 = (const uint2*)&xT[n + 32 + t3][c0];
            b0u.u[0] = p0[0]; b0u.u[1] = p0[1];
            b1u.u[0] = p1[0]; b1u.u[1] = p1[1];
            acc0 = __builtin_amdgcn_mfma_f32_32x32x16_bf16(a, b0u.v, acc0, 0, 0, 0);
            acc1 = __builtin_amdgcn_mfma_f32_32x32x16_bf16(a, b1u.v, acc1, 0, 0, 0);
        }
    }
    #pragma unroll
    for (int r = 0; r < 16; ++r) {
        int m = (r & 3) + 8 * (r >> 2) + 4 * kg;
        int o = w * 32 + m;
        float bias = eb3[e * 128 + o];
        int q = q0 + n;
        if (q < L2LEN)
            atomicAdd(&FINAL[(b * 128 + o) * L2LEN + q], relu_f(acc0[r] + bias) * wk);
        int q2 = q0 + 32 + n;
        if (q2 < L2LEN)
            atomicAdd(&FINAL[(b * 128 + o) * L2LEN + q2], relu_f(acc1[r] + bias) * wk);
    }
}

// ---------------- adaptive max-pool 513 -> 256 ----------------
__global__ __launch_bounds__(256) void maxpool_kernel(const float* __restrict__ FINAL, float* __restrict__ out) {
    int idx = blockIdx.x * 256 + threadIdx.x;
    if (idx >= 128 * 128 * 256) return;
    int j = idx & 255;
    int bo = idx >> 8;
    int s = (j * 513) >> 8;
    int e_ = (j * 513 + 768) >> 8;
    const float* f = FINAL + bo * L2LEN;
    float m = f[s];
    if (s + 1 < e_) m = fmaxf(m, f[s + 1]);
    if (s + 2 < e_) m = fmaxf(m, f[s + 2]);
    out[idx] = m;
}

extern "C" void kernel_launch(void* const* d_in, const int* in_sizes, int n_in,
                              void* d_out, int out_size, void* d_ws, size_t ws_size,
                              hipStream_t stream) {
    const float* x    = (const float*)d_in[0];
    const float* g_w1 = (const float*)d_in[1];
    const float* g_b1 = (const float*)d_in[2];
    const float* g_w2 = (const float*)d_in[3];
    const float* g_b2 = (const float*)d_in[4];
    const float* m_w1 = (const float*)d_in[5];
    const float* m_b1 = (const float*)d_in[6];
    const float* m_w2 = (const float*)d_in[7];
    const float* m_b2 = (const float*)d_in[8];
    const float* ew1  = (const float*)d_in[9];
    const float* eb1  = (const float*)d_in[10];
    const float* ew2  = (const float*)d_in[11];
    const float* eb2  = (const float*)d_in[12];
    const float* ew3  = (const float*)d_in[13];
    const float* eb3  = (const float*)d_in[14];

    float* ws     = (float*)d_ws;
    float* FFT    = ws + OFF_FFT;
    float* TWID   = ws + OFF_TWID;
    float* PTW    = ws + OFF_PTW;
    float* WIN    = ws + OFF_WIN;
    float* PART   = ws + OFF_PART;
    float* TW     = ws + OFF_TW;
    int*   TI     = (int*)(ws + OFF_TI);
    float* SRWLOG = ws + OFF_SRWLOG;
    ushort_t* W2H = (ushort_t*)(ws + OFF_W2H);
    ushort_t* W2L = (ushort_t*)(ws + OFF_W2L);
    ushort_t* EW2P = (ushort_t*)(ws + OFF_EW2P);
    ushort_t* EW3P = (ushort_t*)(ws + OFF_EW3P);
    uint_t* H1P   = (uint_t*)(ws + OFF_A);       // dead after g2
    ushort_t* E1u = (ushort_t*)(ws + OFF_A);     // overlays H1P (e1 runs after mlp)
    ushort_t* E2u = (ushort_t*)(ws + OFF_E2U);
    float* FINAL  = ws + OFF_FINAL;
    float* out    = (float*)d_out;

    init_kernel<<<512, 256, 0, stream>>>(SRWLOG, TWID, PTW, WIN, W2H, W2L, EW2P, EW3P, FINAL, g_w2, ew2, ew3);
    fft_kernel<<<128, 256, 0, stream>>>(x, TWID, PTW, WIN, FFT);
    g1_kernel<<<dim3(9, 128), 256, 0, stream>>>(FFT, g_w1, g_b1, H1P);
    g2_kernel<<<dim3(33, 128), 256, 0, stream>>>(H1P, W2H, W2L, g_b2, PART);
    mlp_kernel<<<128, 128, 0, stream>>>(PART, m_w1, m_b1, m_w2, m_b2, TW, TI, SRWLOG);
    aux_kernel<<<1, 64, 0, stream>>>(SRWLOG, out + 4194304);
    e1_kernel<<<dim3(5, 128, 2), 256, 0, stream>>>(FFT, ew1, eb1, TI, E1u);
    e2_kernel<<<dim3(9, 128, 2), 256, 0, stream>>>(E1u, EW2P, eb2, TI, E2u);
    e3_kernel<<<dim3(9, 128, 2), 256, 0, stream>>>(E2u, EW3P, eb3, TI, TW, FINAL);
    maxpool_kernel<<<16384, 256, 0, stream>>>(FINAL, out);
}

// Round 6
// 362.480 us; speedup vs baseline: 2.7068x; 1.0795x over previous
//
#include <hip/hip_runtime.h>

#define NFREQ 2049
#define L1LEN 1025
#define L1STRIDE 1026
#define L2LEN 513

typedef short v8s  __attribute__((ext_vector_type(8)));
typedef float v16f __attribute__((ext_vector_type(16)));
typedef unsigned short ushort_t;
typedef unsigned int uint_t;

// ---------------- workspace layout (float offsets) ----------------
#define OFF_FFT     0ull          // 524544
#define OFF_TWID    524544ull     // 2048
#define OFF_PTW     526592ull     // 4352
#define OFF_WIN     530944ull     // 4096
#define OFF_PART    535040ull     // 540672
#define OFF_TW      1075712ull    // 256
#define OFF_TI      1075968ull    // 256 (ints)
#define OFF_SRWLOG  1076224ull    // 256
#define OFF_W2H     1076480ull    // 5120
#define OFF_W2L     1081600ull    // 5120
#define OFF_EW2P    1086720ull    // 163840 (ushort 327680)
#define OFF_EW3P    1250560ull    // 196608 (ushort 393216)
#define OFF_A       1447168ull    // 8404992: H1P (uint 8392704) overlaid by E1u[2] (ushort 2*8404992)
#define OFF_E2U     9852160ull    // 8404992: E2u[2] (ushort 2*8404992)
// total 18,257,152 floats ~ 69.6 MiB

#define E1U_K_STRIDE 8404992      // ushort elements per k (128*64*1026)
#define E2U_K_STRIDE 8404992      // ushort elements per k (128*128*513)

__device__ __forceinline__ float relu_f(float x) { return fmaxf(x, 0.0f); }
__device__ __forceinline__ int   rfl_i(int v)   { return __builtin_amdgcn_readfirstlane(v); }
__device__ __forceinline__ float rfl_f(float v) { return __uint_as_float((unsigned)__builtin_amdgcn_readfirstlane((int)__float_as_uint(v))); }
__device__ __forceinline__ ushort_t f2bf(float x) {
    unsigned u = __float_as_uint(x);
    unsigned r = (u + 0x7FFFu + ((u >> 16) & 1u)) >> 16;   // RNE
    return (ushort_t)r;
}
__device__ __forceinline__ float bf2f(ushort_t h) { return __uint_as_float(((unsigned)h) << 16); }

// ---------------- init: tables + zero aux/out + pack weights ----------------
__global__ void init_kernel(float* SRWLOG, float* TWID, float* PTW, float* WIN,
                            ushort_t* W2H, ushort_t* W2L, ushort_t* EW2P, ushort_t* EW3P,
                            float* out0,
                            const float* g_w2, const float* ew2, const float* ew3) {
    const float PI = 3.14159265358979323846f;
    int tid = blockIdx.x * blockDim.x + threadIdx.x;
    int stride = gridDim.x * blockDim.x;
    for (int i = tid; i < 16; i += stride) SRWLOG[i] = 0.0f;
    for (int i = tid; i < 4194304; i += stride) out0[i] = 0.0f;   // maxpool accum base (values >= 0)
    for (int j = tid; j < 1024; j += stride) {
        float a = PI * (float)j / 1024.0f;
        TWID[2 * j] = cosf(a);
        TWID[2 * j + 1] = -sinf(a);
    }
    for (int k = tid; k < 2049; k += stride) {
        float a = PI * (float)k / 2048.0f;
        PTW[2 * k] = cosf(a);
        PTW[2 * k + 1] = sinf(a);
    }
    for (int n = tid; n < 4096; n += stride) {
        WIN[n] = 0.5f * (1.0f - cosf(2.0f * PI * (float)n / 4096.0f));
    }
    // g_w2 (64,32,5) -> W2H/W2L[(t*64+o)*32 + c] split bf16
    for (int i = tid; i < 10240; i += stride) {
        int c = i & 31;
        int o = (i >> 5) & 63;
        int t = i >> 11;
        float w = g_w2[o * 160 + c * 5 + t];
        ushort_t h = f2bf(w);
        W2H[i] = h;
        W2L[i] = f2bf(w - bf2f(h));
    }
    // ew2 (8,128,64,5) -> EW2P[((e*5+t)*128+o)*64 + c] bf16
    for (int i = tid; i < 327680; i += stride) {
        int c = i & 63;
        int o = (i >> 6) & 127;
        int t = (i >> 13) % 5;
        int e = i / 40960;
        EW2P[i] = f2bf(ew2[((e * 128 + o) * 64 + c) * 5 + t]);
    }
    // ew3 (8,128,128,3) -> EW3P[((e*3+t)*128+o)*128 + c] bf16
    for (int i = tid; i < 393216; i += stride) {
        int c = i & 127;
        int o = (i >> 7) & 127;
        int t = (i >> 14) % 3;
        int e = i / 49152;
        EW3P[i] = f2bf(ew3[((e * 128 + o) * 128 + c) * 3 + t]);
    }
}

// ---------------- windowed rfft(4096) via 2048-pt complex FFT (table-driven) ----------------
__global__ __launch_bounds__(256) void fft_kernel(const float* __restrict__ x,
                                                  const float* __restrict__ TWID,
                                                  const float* __restrict__ PTW,
                                                  const float* __restrict__ WIN,
                                                  float* __restrict__ FFT) {
    __shared__ float re[2048];
    __shared__ float im[2048];
    int b = blockIdx.x, t = threadIdx.x;
    const float* xb = x + b * 4096;
    for (int i = t; i < 2048; i += 256) {
        int j = (int)(__brev((unsigned)i) >> 21);   // 11-bit reversal
        re[i] = xb[2 * j] * WIN[2 * j];
        im[i] = xb[2 * j + 1] * WIN[2 * j + 1];
    }
    for (int s = 1; s <= 11; ++s) {
        __syncthreads();
        int half = 1 << (s - 1);
        int shift = 11 - s;
        for (int bf = t; bf < 1024; bf += 256) {
            int grp = bf >> (s - 1);
            int pos = bf & (half - 1);
            int i1 = (grp << s) + pos;
            int i2 = i1 + half;
            int j = pos << shift;
            float wr = TWID[2 * j], wi = TWID[2 * j + 1];
            float ar = re[i2], ai = im[i2];
            float tr = wr * ar - wi * ai;
            float ti = wr * ai + wi * ar;
            float br = re[i1], bi = im[i1];
            re[i2] = br - tr; im[i2] = bi - ti;
            re[i1] = br + tr; im[i1] = bi + ti;
        }
    }
    __syncthreads();
    const float scale = 1.0f / 64.0f;
    for (int k = t; k <= 2048; k += 256) {
        int k1 = k & 2047;
        int k2 = (2048 - k) & 2047;
        float zr = re[k1], zi = im[k1];
        float yr = re[k2], yi = im[k2];
        float Er = 0.5f * (zr + yr), Ei = 0.5f * (zi - yi);
        float Or = 0.5f * (zi + yi), Oi = 0.5f * (yr - zr);
        float c2 = PTW[2 * k], s3 = PTW[2 * k + 1];
        FFT[b * 4098 + k]        = (Er + c2 * Or + s3 * Oi) * scale;
        FFT[b * 4098 + 2049 + k] = (Ei + c2 * Oi - s3 * Or) * scale;
    }
}

// ---------------- gate conv1 -> H1P packed (hi|lo) bf16, layout [b][pos][c] ----------------
__global__ __launch_bounds__(256) void g1_kernel(const float* __restrict__ FFT,
                                                 const float* __restrict__ g_w1, const float* __restrict__ g_b1,
                                                 uint_t* __restrict__ H1P) {
    int pos = blockIdx.x * 256 + threadIdx.x;
    if (pos >= NFREQ) return;
    int b = blockIdx.y;
    const float* fb = FFT + b * 4098;
    float f[2][5];
    #pragma unroll
    for (int cc = 0; cc < 2; ++cc)
        #pragma unroll
        for (int tt = 0; tt < 5; ++tt) {
            int p = pos - 2 + tt;
            f[cc][tt] = (p >= 0 && p < NFREQ) ? fb[cc * NFREQ + p] : 0.0f;
        }
    uint_t* outp = H1P + (b * NFREQ + pos) * 32;
    #pragma unroll
    for (int o = 0; o < 32; ++o) {
        float a = g_b1[o];
        #pragma unroll
        for (int cc = 0; cc < 2; ++cc)
            #pragma unroll
            for (int tt = 0; tt < 5; ++tt)
                a = fmaf(f[cc][tt], g_w1[(o * 2 + cc) * 5 + tt], a);
        a = relu_f(a);
        ushort_t h = f2bf(a);
        ushort_t l = f2bf(a - bf2f(h));
        outp[o] = (uint_t)h | ((uint_t)l << 16);
    }
}

// ---------------- gate conv2 (split-precision MFMA) + partial mean-pool ----------------
__global__ __launch_bounds__(256) void g2_kernel(const uint_t* __restrict__ H1P,
                                                 const ushort_t* __restrict__ W2H, const ushort_t* __restrict__ W2L,
                                                 const float* __restrict__ g_b2,
                                                 float* __restrict__ PART) {
    __shared__ ushort_t xh[68][36];
    __shared__ ushort_t xl[68][36];
    int b = blockIdx.y;
    int q0 = blockIdx.x * 64;
    int t = threadIdx.x;
    for (int i = t; i < 68 * 32; i += 256) {
        int row = i >> 5, c = i & 31;
        int pos = q0 - 2 + row;
        uint_t v = (pos >= 0 && pos < NFREQ) ? H1P[(b * NFREQ + pos) * 32 + c] : 0u;
        xh[row][c] = (ushort_t)(v & 0xFFFFu);
        xl[row][c] = (ushort_t)(v >> 16);
    }
    __syncthreads();
    int lane = t & 63;
    int w = rfl_i(t >> 6);
    int tile_o = (w & 1) * 32;
    int qh = w >> 1;
    int n = lane & 31;
    int kg = lane >> 5;
    v16f acc;
    #pragma unroll
    for (int i = 0; i < 16; ++i) acc[i] = 0.0f;
    #pragma unroll
    for (int t5 = 0; t5 < 5; ++t5) {
        const ushort_t* whp = W2H + (t5 * 64 + tile_o + n) * 32;
        const ushort_t* wlp = W2L + (t5 * 64 + tile_o + n) * 32;
        int row = qh * 32 + n + t5;
        #pragma unroll
        for (int ks = 0; ks < 2; ++ks) {
            int c0 = ks * 16 + kg * 8;
            v8s Ah = *(const v8s*)(whp + c0);
            v8s Al = *(const v8s*)(wlp + c0);
            union { uint2 u[2]; v8s v; } Bh, Bl;
            const uint2* ph = (const uint2*)&xh[row][c0];
            const uint2* pl = (const uint2*)&xl[row][c0];
            Bh.u[0] = ph[0]; Bh.u[1] = ph[1];
            Bl.u[0] = pl[0]; Bl.u[1] = pl[1];
            acc = __builtin_amdgcn_mfma_f32_32x32x16_bf16(Ah, Bh.v, acc, 0, 0, 0);
            acc = __builtin_amdgcn_mfma_f32_32x32x16_bf16(Ah, Bl.v, acc, 0, 0, 0);
            acc = __builtin_amdgcn_mfma_f32_32x32x16_bf16(Al, Bh.v, acc, 0, 0, 0);
        }
    }
    int q = q0 + qh * 32 + n;
    bool valid = (q < NFREQ);
    #pragma unroll
    for (int r = 0; r < 16; ++r) {
        int m = (r & 3) + 8 * (r >> 2) + 4 * kg;
        int o = tile_o + m;
        float v = valid ? relu_f(acc[r] + g_b2[o]) : 0.0f;
        #pragma unroll
        for (int msk = 16; msk >= 1; msk >>= 1) v += __shfl_xor(v, msk, 64);
        if (n == 0) PART[(b * 64 + o) * 66 + blockIdx.x * 2 + qh] = v;
    }
}

// ---------------- router MLP + softmax + top2 + aux partials ----------------
__global__ __launch_bounds__(128) void mlp_kernel(const float* __restrict__ PART,
                                                  const float* __restrict__ m_w1, const float* __restrict__ m_b1,
                                                  const float* __restrict__ m_w2, const float* __restrict__ m_b2,
                                                  float* TW, int* TI, float* SRWLOG) {
    __shared__ float pooledS[64];
    __shared__ float hid[128];
    __shared__ float lgS[8];
    __shared__ float rwS[8];
    int b = blockIdx.x, t = threadIdx.x;
    if (t < 64) {
        float s = 0.0f;
        const float* pp = PART + (b * 64 + t) * 66;
        for (int blk = 0; blk < 66; ++blk) s += pp[blk];
        pooledS[t] = s;
    }
    __syncthreads();
    const float inv = 1.0f / 2049.0f;
    {
        float h = m_b1[t];
        for (int c = 0; c < 64; ++c)
            h = fmaf(pooledS[c] * inv, m_w1[t * 64 + c], h);
        hid[t] = relu_f(h);
    }
    __syncthreads();
    if (t < 8) {
        float lg = m_b2[t];
        for (int j = 0; j < 128; ++j) lg = fmaf(hid[j], m_w2[t * 128 + j], lg);
        lgS[t] = lg;
    }
    __syncthreads();
    if (t == 0) {
        float mx = lgS[0];
        for (int e = 1; e < 8; ++e) mx = fmaxf(mx, lgS[e]);
        float s = 0.0f, ex[8];
        for (int e = 0; e < 8; ++e) { ex[e] = expf(lgS[e] - mx); s += ex[e]; }
        for (int e = 0; e < 8; ++e) rwS[e] = ex[e] / s;
        int i1 = 0;
        for (int e = 1; e < 8; ++e) if (rwS[e] > rwS[i1]) i1 = e;
        int i2 = (i1 == 0) ? 1 : 0;
        for (int e = 0; e < 8; ++e) if (e != i1 && rwS[e] > rwS[i2]) i2 = e;
        float t0 = rwS[i1], t1 = rwS[i2], sm = t0 + t1;
        TW[b * 2] = t0 / sm; TW[b * 2 + 1] = t1 / sm;
        TI[b * 2] = i1; TI[b * 2 + 1] = i2;
    }
    __syncthreads();
    if (t < 8) {
        atomicAdd(&SRWLOG[t], rwS[t]);
        atomicAdd(&SRWLOG[8 + t], lgS[t]);
    }
}

__global__ void aux_kernel(const float* SRWLOG, float* out_aux) {
    if (threadIdx.x == 0 && blockIdx.x == 0) {
        float a = 0.0f;
        for (int e = 0; e < 8; ++e)
            a += (SRWLOG[e] / 128.0f) * (SRWLOG[8 + e] / 128.0f);
        out_aux[0] = 0.01f * 8.0f * a;
    }
}

// ---------------- expert conv1: (2->64, k=7, s=2, p=3), bf16 out, row stride 1026 ----------------
__global__ __launch_bounds__(256) void e1_kernel(const float* __restrict__ FFT,
                                                 const float* __restrict__ ew1, const float* __restrict__ eb1,
                                                 const int* __restrict__ TI, ushort_t* __restrict__ E1u) {
    __shared__ float xs[2][520];
    int r0 = blockIdx.x * 256;
    int b = blockIdx.y;
    int k = blockIdx.z;
    int t = threadIdx.x;
    int e = rfl_i(TI[b * 2 + k]);
    int lo = 2 * r0 - 3;
    const float* fb = FFT + b * 4098;
    for (int i = t; i < 2 * 520; i += 256) {
        int ch = i / 520, off = i % 520;
        int pos = lo + off;
        xs[ch][off] = (pos >= 0 && pos < NFREQ) ? fb[ch * NFREQ + pos] : 0.0f;
    }
    __syncthreads();
    int r = r0 + t;
    if (r >= L1LEN) return;
    float xv[14];
    #pragma unroll
    for (int ch = 0; ch < 2; ++ch)
        #pragma unroll
        for (int tt = 0; tt < 7; ++tt)
            xv[ch * 7 + tt] = xs[ch][2 * t + tt];
    const float* wb = ew1 + e * 64 * 14;
    const float* bb = eb1 + e * 64;
    ushort_t* outb = E1u + (size_t)k * E1U_K_STRIDE + (size_t)b * 64 * L1STRIDE + r;
    bool last = (r == L1LEN - 1);
    for (int o = 0; o < 64; ++o) {
        float a = bb[o];
        const float* w = wb + o * 14;
        #pragma unroll
        for (int j = 0; j < 14; ++j)
            a = fmaf(xv[j], w[j], a);
        outb[o * L1STRIDE] = f2bf(relu_f(a));
        if (last) outb[o * L1STRIDE + 1] = 0;   // zero pad slot 1025 for e2's uint loads
    }
}

// ---------------- expert conv2 (MFMA): (64->128, k=5, s=2, p=2) ----------------
// grid (9, 128, 2); staging via aligned uint loads (even|odd pair)
__global__ __launch_bounds__(256) void e2_kernel(const ushort_t* __restrict__ E1u,
                                                 const ushort_t* __restrict__ EW2P, const float* __restrict__ eb2,
                                                 const int* __restrict__ TI, ushort_t* __restrict__ E2u) {
    __shared__ ushort_t xe[66][68];
    __shared__ ushort_t xo[66][68];
    int b = blockIdx.y;
    int k = blockIdx.z;
    int q0 = blockIdx.x * 64;
    int t = threadIdx.x;
    int e = rfl_i(TI[b * 2 + k]);
    const ushort_t* E1k = E1u + (size_t)k * E1U_K_STRIDE;
    for (int i = t; i < 64 * 66; i += 256) {
        int c = i / 66, j = i % 66;
        int p = 2 * q0 - 2 + 2 * j;          // even position; pair (p, p+1)
        uint_t v = 0;
        if (p >= 0 && p < L1LEN)             // p==1024 ok: slot 1025 is zeroed pad
            v = *(const uint_t*)(E1k + (size_t)(b * 64 + c) * L1STRIDE + p);
        xe[j][c] = (ushort_t)(v & 0xFFFFu);
        xo[j][c] = (ushort_t)(v >> 16);
    }
    __syncthreads();
    int lane = t & 63;
    int w = rfl_i(t >> 6);
    int n = lane & 31;
    int kg = lane >> 5;
    v16f acc0, acc1;
    #pragma unroll
    for (int i = 0; i < 16; ++i) { acc0[i] = 0.0f; acc1[i] = 0.0f; }
    #pragma unroll
    for (int t5 = 0; t5 < 5; ++t5) {
        const ushort_t* wrow = EW2P + (((e * 5 + t5) * 128) + w * 32 + n) * 64;
        int roff = t5 >> 1;
        const ushort_t (*sel)[68] = (t5 & 1) ? xo : xe;
        #pragma unroll
        for (int ks = 0; ks < 4; ++ks) {
            int c0 = ks * 16 + kg * 8;
            v8s a = *(const v8s*)(wrow + c0);
            union { uint2 u[2]; v8s v; } b0u, b1u;
            const uint2* p0 = (const uint2*)&sel[n + roff][c0];
            const uint2* p1 = (const uint2*)&sel[n + 32 + roff][c0];
            b0u.u[0] = p0[0]; b0u.u[1] = p0[1];
            b1u.u[0] = p1[0]; b1u.u[1] = p1[1];
            acc0 = __builtin_amdgcn_mfma_f32_32x32x16_bf16(a, b0u.v, acc0, 0, 0, 0);
            acc1 = __builtin_amdgcn_mfma_f32_32x32x16_bf16(a, b1u.v, acc1, 0, 0, 0);
        }
    }
    ushort_t* E2k = E2u + (size_t)k * E2U_K_STRIDE;
    #pragma unroll
    for (int r = 0; r < 16; ++r) {
        int m = (r & 3) + 8 * (r >> 2) + 4 * kg;
        int o = w * 32 + m;
        float bias = eb2[e * 128 + o];
        int q = q0 + n;
        if (q < L2LEN)      E2k[(b * 128 + o) * L2LEN + q]  = f2bf(relu_f(acc0[r] + bias));
        int q2 = q0 + 32 + n;
        if (q2 < L2LEN)     E2k[(b * 128 + o) * L2LEN + q2] = f2bf(relu_f(acc1[r] + bias));
    }
}

// ---------------- expert conv3 (MFMA, both k in-block) + fused adaptive max-pool ----------------
// grid (9, 128). LDS: union of staging tile (17.4 KB) and output tile (32 KB).
__global__ __launch_bounds__(256) void e3_kernel(const ushort_t* __restrict__ E2u,
                                                 const ushort_t* __restrict__ EW3P, const float* __restrict__ eb3,
                                                 const int* __restrict__ TI, const float* __restrict__ TW,
                                                 float* __restrict__ out) {
    __shared__ __align__(16) char smem[32768];
    ushort_t (*xT)[132] = (ushort_t (*)[132])smem;   // [66][132]
    float (*fT)[64] = (float (*)[64])smem;           // [128][64]
    int b = blockIdx.y;
    int q0 = blockIdx.x * 64;
    int t = threadIdx.x;
    int lane = t & 63;
    int w = rfl_i(t >> 6);
    int n = lane & 31;
    int kg = lane >> 5;
    float res0[16], res1[16];
    #pragma unroll
    for (int i = 0; i < 16; ++i) { res0[i] = 0.0f; res1[i] = 0.0f; }
    for (int k = 0; k < 2; ++k) {
        int e = rfl_i(TI[b * 2 + k]);
        float wk = rfl_f(TW[b * 2 + k]);
        const ushort_t* E2k = E2u + (size_t)k * E2U_K_STRIDE;
        __syncthreads();   // previous pass's xT reads done
        for (int i = t; i < 128 * 66; i += 256) {
            int c = i / 66, row = i % 66;
            int pos = q0 - 1 + row;
            xT[row][c] = (pos >= 0 && pos < L2LEN) ? E2k[(b * 128 + c) * L2LEN + pos] : (ushort_t)0;
        }
        __syncthreads();
        v16f acc0, acc1;
        #pragma unroll
        for (int i = 0; i < 16; ++i) { acc0[i] = 0.0f; acc1[i] = 0.0f; }
        #pragma unroll
        for (int t3 = 0; t3 < 3; ++t3) {
            const ushort_t* wrow = EW3P + (((e * 3 + t3) * 128) + w * 32 + n) * 128;
            #pragma unroll
            for (int ks = 0; ks < 8; ++ks) {
                int c0 = ks * 16 + kg * 8;
                v8s a = *(const v8s*)(wrow + c0);
                union { uint2 u[2]; v8s v; } b0u, b1u;
                const uint2* p0 = (const uint2*)&xT[n + t3][c0];
                const uint2* p1 = (const uint2*)&xT[n + 32 + t3][c0];
                b0u.u[0] = p0[0]; b0u.u[1] = p0[1];
                b1u.u[0] = p1[0]; b1u.u[1] = p1[1];
                acc0 = __builtin_amdgcn_mfma_f32_32x32x16_bf16(a, b0u.v, acc0, 0, 0, 0);
                acc1 = __builtin_amdgcn_mfma_f32_32x32x16_bf16(a, b1u.v, acc1, 0, 0, 0);
            }
        }
        #pragma unroll
        for (int r = 0; r < 16; ++r) {
            int m = (r & 3) + 8 * (r >> 2) + 4 * kg;
            float bias = eb3[e * 128 + w * 32 + m];
            res0[r] += relu_f(acc0[r] + bias) * wk;
            res1[r] += relu_f(acc1[r] + bias) * wk;
        }
    }
    __syncthreads();   // xT fully dead; smem becomes fT
    #pragma unroll
    for (int r = 0; r < 16; ++r) {
        int m = (r & 3) + 8 * (r >> 2) + 4 * kg;
        int o = w * 32 + m;
        fT[o][n]      = (q0 + n      < L2LEN) ? res0[r] : 0.0f;
        fT[o][32 + n] = (q0 + 32 + n < L2LEN) ? res1[r] : 0.0f;
    }
    __syncthreads();
    // adaptive max-pool: outputs j with window [s,e) intersecting [q0, qvend)
    int qvend = min(q0 + 64, L2LEN);
    int j_lo = (q0 * 256) / 513;
    while (j_lo > 0 && ((513 * j_lo + 255 + 513) >> 8) > q0) --j_lo;       // e(j_lo-1) > q0 ? step back
    while (((513 * (j_lo + 1) + 255) >> 8) <= q0) ++j_lo;                  // ensure e(j_lo) > q0
    int j_hi = min(255, ((qvend * 256) / 513) + 1);
    while (((513 * j_hi) >> 8) >= qvend) --j_hi;                           // ensure s(j_hi) < qvend
    int oo = t >> 1;
    for (int j = j_lo + (t & 1); j <= j_hi; j += 2) {
        int s = (513 * j) >> 8;
        int e_ = (513 * (j + 1) + 255) >> 8;
        int lo = max(s, q0), hi = min(e_, qvend);
        float m = fT[oo][lo - q0];
        for (int p = lo + 1; p < hi; ++p) m = fmaxf(m, fT[oo][p - q0]);
        int idx = (b * 128 + oo) * 256 + j;
        if (s >= q0 && e_ <= qvend) out[idx] = m;                          // interior: sole writer
        else atomicMax((int*)out + idx, __float_as_int(m));                // straddler: values >= 0
    }
}

extern "C" void kernel_launch(void* const* d_in, const int* in_sizes, int n_in,
                              void* d_out, int out_size, void* d_ws, size_t ws_size,
                              hipStream_t stream) {
    const float* x    = (const float*)d_in[0];
    const float* g_w1 = (const float*)d_in[1];
    const float* g_b1 = (const float*)d_in[2];
    const float* g_w2 = (const float*)d_in[3];
    const float* g_b2 = (const float*)d_in[4];
    const float* m_w1 = (const float*)d_in[5];
    const float* m_b1 = (const float*)d_in[6];
    const float* m_w2 = (const float*)d_in[7];
    const float* m_b2 = (const float*)d_in[8];
    const float* ew1  = (const float*)d_in[9];
    const float* eb1  = (const float*)d_in[10];
    const float* ew2  = (const float*)d_in[11];
    const float* eb2  = (const float*)d_in[12];
    const float* ew3  = (const float*)d_in[13];
    const float* eb3  = (const float*)d_in[14];

    float* ws     = (float*)d_ws;
    float* FFT    = ws + OFF_FFT;
    float* TWID   = ws + OFF_TWID;
    float* PTW    = ws + OFF_PTW;
    float* WIN    = ws + OFF_WIN;
    float* PART   = ws + OFF_PART;
    float* TW     = ws + OFF_TW;
    int*   TI     = (int*)(ws + OFF_TI);
    float* SRWLOG = ws + OFF_SRWLOG;
    ushort_t* W2H = (ushort_t*)(ws + OFF_W2H);
    ushort_t* W2L = (ushort_t*)(ws + OFF_W2L);
    ushort_t* EW2P = (ushort_t*)(ws + OFF_EW2P);
    ushort_t* EW3P = (ushort_t*)(ws + OFF_EW3P);
    uint_t* H1P   = (uint_t*)(ws + OFF_A);       // dead after g2
    ushort_t* E1u = (ushort_t*)(ws + OFF_A);     // overlays H1P (e1 runs after g2/mlp)
    ushort_t* E2u = (ushort_t*)(ws + OFF_E2U);
    float* out    = (float*)d_out;

    init_kernel<<<512, 256, 0, stream>>>(SRWLOG, TWID, PTW, WIN, W2H, W2L, EW2P, EW3P, out, g_w2, ew2, ew3);
    fft_kernel<<<128, 256, 0, stream>>>(x, TWID, PTW, WIN, FFT);
    g1_kernel<<<dim3(9, 128), 256, 0, stream>>>(FFT, g_w1, g_b1, H1P);
    g2_kernel<<<dim3(33, 128), 256, 0, stream>>>(H1P, W2H, W2L, g_b2, PART);
    mlp_kernel<<<128, 128, 0, stream>>>(PART, m_w1, m_b1, m_w2, m_b2, TW, TI, SRWLOG);
    aux_kernel<<<1, 64, 0, stream>>>(SRWLOG, out + 4194304);
    e1_kernel<<<dim3(5, 128, 2), 256, 0, stream>>>(FFT, ew1, eb1, TI, E1u);
    e2_kernel<<<dim3(9, 128, 2), 256, 0, stream>>>(E1u, EW2P, eb2, TI, E2u);
    e3_kernel<<<dim3(9, 128), 256, 0, stream>>>(E2u, EW3P, eb3, TI, TW, out);
}

// Round 7
// 328.874 us; speedup vs baseline: 2.9834x; 1.1022x over previous
//
#include <hip/hip_runtime.h>

#define NFREQ 2049
#define L1LEN 1025
#define L1STRIDE 1026
#define L2LEN 513

typedef short v8s  __attribute__((ext_vector_type(8)));
typedef float v16f __attribute__((ext_vector_type(16)));
typedef unsigned short ushort_t;
typedef unsigned int uint_t;

// ---------------- workspace layout (float offsets) ----------------
#define OFF_FFT     0ull          // 524544
#define OFF_TWID    524544ull     // 2048
#define OFF_PTW     526592ull     // 4352
#define OFF_WIN     530944ull     // 4096
#define OFF_PART    535040ull     // 540672
#define OFF_TW      1075712ull    // 256
#define OFF_TI      1075968ull    // 256 (ints)
#define OFF_SRWLOG  1076224ull    // 256
#define OFF_W2H     1076480ull    // 5120
#define OFF_W2L     1081600ull    // 5120
#define OFF_EW2P    1086720ull    // 163840 (ushort 327680)
#define OFF_EW3P    1250560ull    // 196608 (ushort 393216)
#define OFF_A       1447168ull    // 8404992: H1P (uint 8392704) overlaid by E1u[2] (ushort 2*8404992)
#define OFF_E2U     9852160ull    // 8404992: E2u[2] (ushort 2*8404992), layout [b][q][c]
// total 18,257,152 floats ~ 69.6 MiB

#define E1U_K_STRIDE 8404992      // ushort elements per k (128*64*1026)
#define E2U_K_STRIDE 8404992      // ushort elements per k (128*513*128)

__device__ __forceinline__ float relu_f(float x) { return fmaxf(x, 0.0f); }
__device__ __forceinline__ int   rfl_i(int v)   { return __builtin_amdgcn_readfirstlane(v); }
__device__ __forceinline__ float rfl_f(float v) { return __uint_as_float((unsigned)__builtin_amdgcn_readfirstlane((int)__float_as_uint(v))); }
__device__ __forceinline__ ushort_t f2bf(float x) {
    unsigned u = __float_as_uint(x);
    unsigned r = (u + 0x7FFFu + ((u >> 16) & 1u)) >> 16;   // RNE
    return (ushort_t)r;
}
__device__ __forceinline__ float bf2f(ushort_t h) { return __uint_as_float(((unsigned)h) << 16); }

// ---------------- init: tables + zero aux/out + pack weights ----------------
__global__ void init_kernel(float* SRWLOG, float* TWID, float* PTW, float* WIN,
                            ushort_t* W2H, ushort_t* W2L, ushort_t* EW2P, ushort_t* EW3P,
                            float* out0,
                            const float* g_w2, const float* ew2, const float* ew3) {
    const float PI = 3.14159265358979323846f;
    int tid = blockIdx.x * blockDim.x + threadIdx.x;
    int stride = gridDim.x * blockDim.x;
    for (int i = tid; i < 16; i += stride) SRWLOG[i] = 0.0f;
    for (int i = tid; i < 4194304; i += stride) out0[i] = 0.0f;   // maxpool accum base (values >= 0)
    for (int j = tid; j < 1024; j += stride) {
        float a = PI * (float)j / 1024.0f;
        TWID[2 * j] = cosf(a);
        TWID[2 * j + 1] = -sinf(a);
    }
    for (int k = tid; k < 2049; k += stride) {
        float a = PI * (float)k / 2048.0f;
        PTW[2 * k] = cosf(a);
        PTW[2 * k + 1] = sinf(a);
    }
    for (int n = tid; n < 4096; n += stride) {
        WIN[n] = 0.5f * (1.0f - cosf(2.0f * PI * (float)n / 4096.0f));
    }
    // g_w2 (64,32,5) -> W2H/W2L[(t*64+o)*32 + c] split bf16
    for (int i = tid; i < 10240; i += stride) {
        int c = i & 31;
        int o = (i >> 5) & 63;
        int t = i >> 11;
        float w = g_w2[o * 160 + c * 5 + t];
        ushort_t h = f2bf(w);
        W2H[i] = h;
        W2L[i] = f2bf(w - bf2f(h));
    }
    // ew2 (8,128,64,5) -> EW2P[((e*5+t)*128+o)*64 + c] bf16
    for (int i = tid; i < 327680; i += stride) {
        int c = i & 63;
        int o = (i >> 6) & 127;
        int t = (i >> 13) % 5;
        int e = i / 40960;
        EW2P[i] = f2bf(ew2[((e * 128 + o) * 64 + c) * 5 + t]);
    }
    // ew3 (8,128,128,3) -> EW3P[((e*3+t)*128+o)*128 + c] bf16
    for (int i = tid; i < 393216; i += stride) {
        int c = i & 127;
        int o = (i >> 7) & 127;
        int t = (i >> 14) % 3;
        int e = i / 49152;
        EW3P[i] = f2bf(ew3[((e * 128 + o) * 128 + c) * 3 + t]);
    }
}

// ---------------- windowed rfft(4096) via 2048-pt complex FFT (table-driven) ----------------
__global__ __launch_bounds__(256) void fft_kernel(const float* __restrict__ x,
                                                  const float* __restrict__ TWID,
                                                  const float* __restrict__ PTW,
                                                  const float* __restrict__ WIN,
                                                  float* __restrict__ FFT) {
    __shared__ float re[2048];
    __shared__ float im[2048];
    int b = blockIdx.x, t = threadIdx.x;
    const float* xb = x + b * 4096;
    for (int i = t; i < 2048; i += 256) {
        int j = (int)(__brev((unsigned)i) >> 21);   // 11-bit reversal
        re[i] = xb[2 * j] * WIN[2 * j];
        im[i] = xb[2 * j + 1] * WIN[2 * j + 1];
    }
    for (int s = 1; s <= 11; ++s) {
        __syncthreads();
        int half = 1 << (s - 1);
        int shift = 11 - s;
        for (int bf = t; bf < 1024; bf += 256) {
            int grp = bf >> (s - 1);
            int pos = bf & (half - 1);
            int i1 = (grp << s) + pos;
            int i2 = i1 + half;
            int j = pos << shift;
            float wr = TWID[2 * j], wi = TWID[2 * j + 1];
            float ar = re[i2], ai = im[i2];
            float tr = wr * ar - wi * ai;
            float ti = wr * ai + wi * ar;
            float br = re[i1], bi = im[i1];
            re[i2] = br - tr; im[i2] = bi - ti;
            re[i1] = br + tr; im[i1] = bi + ti;
        }
    }
    __syncthreads();
    const float scale = 1.0f / 64.0f;
    for (int k = t; k <= 2048; k += 256) {
        int k1 = k & 2047;
        int k2 = (2048 - k) & 2047;
        float zr = re[k1], zi = im[k1];
        float yr = re[k2], yi = im[k2];
        float Er = 0.5f * (zr + yr), Ei = 0.5f * (zi - yi);
        float Or = 0.5f * (zi + yi), Oi = 0.5f * (yr - zr);
        float c2 = PTW[2 * k], s3 = PTW[2 * k + 1];
        FFT[b * 4098 + k]        = (Er + c2 * Or + s3 * Oi) * scale;
        FFT[b * 4098 + 2049 + k] = (Ei + c2 * Oi - s3 * Or) * scale;
    }
}

// ---------------- gate conv1 -> H1P packed (hi|lo) bf16, layout [b][pos][c] ----------------
__global__ __launch_bounds__(256) void g1_kernel(const float* __restrict__ FFT,
                                                 const float* __restrict__ g_w1, const float* __restrict__ g_b1,
                                                 uint_t* __restrict__ H1P) {
    int pos = blockIdx.x * 256 + threadIdx.x;
    if (pos >= NFREQ) return;
    int b = blockIdx.y;
    const float* fb = FFT + b * 4098;
    float f[2][5];
    #pragma unroll
    for (int cc = 0; cc < 2; ++cc)
        #pragma unroll
        for (int tt = 0; tt < 5; ++tt) {
            int p = pos - 2 + tt;
            f[cc][tt] = (p >= 0 && p < NFREQ) ? fb[cc * NFREQ + p] : 0.0f;
        }
    uint_t* outp = H1P + (b * NFREQ + pos) * 32;
    #pragma unroll
    for (int o = 0; o < 32; ++o) {
        float a = g_b1[o];
        #pragma unroll
        for (int cc = 0; cc < 2; ++cc)
            #pragma unroll
            for (int tt = 0; tt < 5; ++tt)
                a = fmaf(f[cc][tt], g_w1[(o * 2 + cc) * 5 + tt], a);
        a = relu_f(a);
        ushort_t h = f2bf(a);
        ushort_t l = f2bf(a - bf2f(h));
        outp[o] = (uint_t)h | ((uint_t)l << 16);
    }
}

// ---------------- gate conv2 (split-precision MFMA) + partial mean-pool ----------------
__global__ __launch_bounds__(256) void g2_kernel(const uint_t* __restrict__ H1P,
                                                 const ushort_t* __restrict__ W2H, const ushort_t* __restrict__ W2L,
                                                 const float* __restrict__ g_b2,
                                                 float* __restrict__ PART) {
    __shared__ ushort_t xh[68][36];
    __shared__ ushort_t xl[68][36];
    int b = blockIdx.y;
    int q0 = blockIdx.x * 64;
    int t = threadIdx.x;
    for (int i = t; i < 68 * 32; i += 256) {
        int row = i >> 5, c = i & 31;
        int pos = q0 - 2 + row;
        uint_t v = (pos >= 0 && pos < NFREQ) ? H1P[(b * NFREQ + pos) * 32 + c] : 0u;
        xh[row][c] = (ushort_t)(v & 0xFFFFu);
        xl[row][c] = (ushort_t)(v >> 16);
    }
    __syncthreads();
    int lane = t & 63;
    int w = rfl_i(t >> 6);
    int tile_o = (w & 1) * 32;
    int qh = w >> 1;
    int n = lane & 31;
    int kg = lane >> 5;
    v16f acc;
    #pragma unroll
    for (int i = 0; i < 16; ++i) acc[i] = 0.0f;
    #pragma unroll
    for (int t5 = 0; t5 < 5; ++t5) {
        const ushort_t* whp = W2H + (t5 * 64 + tile_o + n) * 32;
        const ushort_t* wlp = W2L + (t5 * 64 + tile_o + n) * 32;
        int row = qh * 32 + n + t5;
        #pragma unroll
        for (int ks = 0; ks < 2; ++ks) {
            int c0 = ks * 16 + kg * 8;
            v8s Ah = *(const v8s*)(whp + c0);
            v8s Al = *(const v8s*)(wlp + c0);
            union { uint2 u[2]; v8s v; } Bh, Bl;
            const uint2* ph = (const uint2*)&xh[row][c0];
            const uint2* pl = (const uint2*)&xl[row][c0];
            Bh.u[0] = ph[0]; Bh.u[1] = ph[1];
            Bl.u[0] = pl[0]; Bl.u[1] = pl[1];
            acc = __builtin_amdgcn_mfma_f32_32x32x16_bf16(Ah, Bh.v, acc, 0, 0, 0);
            acc = __builtin_amdgcn_mfma_f32_32x32x16_bf16(Ah, Bl.v, acc, 0, 0, 0);
            acc = __builtin_amdgcn_mfma_f32_32x32x16_bf16(Al, Bh.v, acc, 0, 0, 0);
        }
    }
    int q = q0 + qh * 32 + n;
    bool valid = (q < NFREQ);
    #pragma unroll
    for (int r = 0; r < 16; ++r) {
        int m = (r & 3) + 8 * (r >> 2) + 4 * kg;
        int o = tile_o + m;
        float v = valid ? relu_f(acc[r] + g_b2[o]) : 0.0f;
        #pragma unroll
        for (int msk = 16; msk >= 1; msk >>= 1) v += __shfl_xor(v, msk, 64);
        if (n == 0) PART[(b * 64 + o) * 66 + blockIdx.x * 2 + qh] = v;
    }
}

// ---------------- router MLP + softmax + top2 + aux partials ----------------
__global__ __launch_bounds__(128) void mlp_kernel(const float* __restrict__ PART,
                                                  const float* __restrict__ m_w1, const float* __restrict__ m_b1,
                                                  const float* __restrict__ m_w2, const float* __restrict__ m_b2,
                                                  float* TW, int* TI, float* SRWLOG) {
    __shared__ float pooledS[64];
    __shared__ float hid[128];
    __shared__ float lgS[8];
    __shared__ float rwS[8];
    int b = blockIdx.x, t = threadIdx.x;
    if (t < 64) {
        float s = 0.0f;
        const float* pp = PART + (b * 64 + t) * 66;
        for (int blk = 0; blk < 66; ++blk) s += pp[blk];
        pooledS[t] = s;
    }
    __syncthreads();
    const float inv = 1.0f / 2049.0f;
    {
        float h = m_b1[t];
        for (int c = 0; c < 64; ++c)
            h = fmaf(pooledS[c] * inv, m_w1[t * 64 + c], h);
        hid[t] = relu_f(h);
    }
    __syncthreads();
    if (t < 8) {
        float lg = m_b2[t];
        for (int j = 0; j < 128; ++j) lg = fmaf(hid[j], m_w2[t * 128 + j], lg);
        lgS[t] = lg;
    }
    __syncthreads();
    if (t == 0) {
        float mx = lgS[0];
        for (int e = 1; e < 8; ++e) mx = fmaxf(mx, lgS[e]);
        float s = 0.0f, ex[8];
        for (int e = 0; e < 8; ++e) { ex[e] = expf(lgS[e] - mx); s += ex[e]; }
        for (int e = 0; e < 8; ++e) rwS[e] = ex[e] / s;
        int i1 = 0;
        for (int e = 1; e < 8; ++e) if (rwS[e] > rwS[i1]) i1 = e;
        int i2 = (i1 == 0) ? 1 : 0;
        for (int e = 0; e < 8; ++e) if (e != i1 && rwS[e] > rwS[i2]) i2 = e;
        float t0 = rwS[i1], t1 = rwS[i2], sm = t0 + t1;
        TW[b * 2] = t0 / sm; TW[b * 2 + 1] = t1 / sm;
        TI[b * 2] = i1; TI[b * 2 + 1] = i2;
    }
    __syncthreads();
    if (t < 8) {
        atomicAdd(&SRWLOG[t], rwS[t]);
        atomicAdd(&SRWLOG[8 + t], lgS[t]);
    }
}

__global__ void aux_kernel(const float* SRWLOG, float* out_aux) {
    if (threadIdx.x == 0 && blockIdx.x == 0) {
        float a = 0.0f;
        for (int e = 0; e < 8; ++e)
            a += (SRWLOG[e] / 128.0f) * (SRWLOG[8 + e] / 128.0f);
        out_aux[0] = 0.01f * 8.0f * a;
    }
}

// ---------------- expert conv1: (2->64, k=7, s=2, p=3), bf16 out, row stride 1026 ----------------
__global__ __launch_bounds__(256) void e1_kernel(const float* __restrict__ FFT,
                                                 const float* __restrict__ ew1, const float* __restrict__ eb1,
                                                 const int* __restrict__ TI, ushort_t* __restrict__ E1u) {
    __shared__ float xs[2][520];
    int r0 = blockIdx.x * 256;
    int b = blockIdx.y;
    int k = blockIdx.z;
    int t = threadIdx.x;
    int e = rfl_i(TI[b * 2 + k]);
    int lo = 2 * r0 - 3;
    const float* fb = FFT + b * 4098;
    for (int i = t; i < 2 * 520; i += 256) {
        int ch = i / 520, off = i % 520;
        int pos = lo + off;
        xs[ch][off] = (pos >= 0 && pos < NFREQ) ? fb[ch * NFREQ + pos] : 0.0f;
    }
    __syncthreads();
    int r = r0 + t;
    if (r >= L1LEN) return;
    float xv[14];
    #pragma unroll
    for (int ch = 0; ch < 2; ++ch)
        #pragma unroll
        for (int tt = 0; tt < 7; ++tt)
            xv[ch * 7 + tt] = xs[ch][2 * t + tt];
    const float* wb = ew1 + e * 64 * 14;
    const float* bb = eb1 + e * 64;
    ushort_t* outb = E1u + (size_t)k * E1U_K_STRIDE + (size_t)b * 64 * L1STRIDE + r;
    bool last = (r == L1LEN - 1);
    for (int o = 0; o < 64; ++o) {
        float a = bb[o];
        const float* w = wb + o * 14;
        #pragma unroll
        for (int j = 0; j < 14; ++j)
            a = fmaf(xv[j], w[j], a);
        outb[o * L1STRIDE] = f2bf(relu_f(a));
        if (last) outb[o * L1STRIDE + 1] = 0;   // zero pad slot 1025 for e2's uint loads
    }
}

// ---------------- expert conv2 (MFMA): (64->128, k=5, s=2, p=2) -> E2 [b][q][c] ----------------
// grid (9, 128, 2); epilogue transposes through LDS for coalesced 16B stores
__global__ __launch_bounds__(256) void e2_kernel(const ushort_t* __restrict__ E1u,
                                                 const ushort_t* __restrict__ EW2P, const float* __restrict__ eb2,
                                                 const int* __restrict__ TI, ushort_t* __restrict__ E2u) {
    __shared__ __align__(16) char sm2[17952];
    ushort_t (*xe)[68] = (ushort_t (*)[68])sm2;            // [66][68]
    ushort_t (*xo)[68] = (ushort_t (*)[68])(sm2 + 8976);   // [66][68]
    ushort_t (*oT)[136] = (ushort_t (*)[136])sm2;          // [64][136] (reuses sm2 after MFMA)
    int b = blockIdx.y;
    int k = blockIdx.z;
    int q0 = blockIdx.x * 64;
    int t = threadIdx.x;
    int e = rfl_i(TI[b * 2 + k]);
    const ushort_t* E1k = E1u + (size_t)k * E1U_K_STRIDE;
    for (int i = t; i < 64 * 66; i += 256) {
        int c = i / 66, j = i % 66;
        int p = 2 * q0 - 2 + 2 * j;          // even position; pair (p, p+1)
        uint_t v = 0;
        if (p >= 0 && p < L1LEN)             // p==1024 ok: slot 1025 is zeroed pad
            v = *(const uint_t*)(E1k + (size_t)(b * 64 + c) * L1STRIDE + p);
        xe[j][c] = (ushort_t)(v & 0xFFFFu);
        xo[j][c] = (ushort_t)(v >> 16);
    }
    __syncthreads();
    int lane = t & 63;
    int w = rfl_i(t >> 6);
    int n = lane & 31;
    int kg = lane >> 5;
    v16f acc0, acc1;
    #pragma unroll
    for (int i = 0; i < 16; ++i) { acc0[i] = 0.0f; acc1[i] = 0.0f; }
    #pragma unroll
    for (int t5 = 0; t5 < 5; ++t5) {
        const ushort_t* wrow = EW2P + (((e * 5 + t5) * 128) + w * 32 + n) * 64;
        int roff = t5 >> 1;
        const ushort_t (*sel)[68] = (t5 & 1) ? xo : xe;
        #pragma unroll
        for (int ks = 0; ks < 4; ++ks) {
            int c0 = ks * 16 + kg * 8;
            v8s a = *(const v8s*)(wrow + c0);
            union { uint2 u[2]; v8s v; } b0u, b1u;
            const uint2* p0 = (const uint2*)&sel[n + roff][c0];
            const uint2* p1 = (const uint2*)&sel[n + 32 + roff][c0];
            b0u.u[0] = p0[0]; b0u.u[1] = p0[1];
            b1u.u[0] = p1[0]; b1u.u[1] = p1[1];
            acc0 = __builtin_amdgcn_mfma_f32_32x32x16_bf16(a, b0u.v, acc0, 0, 0, 0);
            acc1 = __builtin_amdgcn_mfma_f32_32x32x16_bf16(a, b1u.v, acc1, 0, 0, 0);
        }
    }
    __syncthreads();   // xe/xo dead -> oT
    #pragma unroll
    for (int g = 0; g < 4; ++g) {
        int ob = w * 32 + 8 * g + 4 * kg;    // 4 consecutive o per C-frag quad
        uint_t p00 = (uint_t)f2bf(relu_f(acc0[4 * g + 0] + eb2[e * 128 + ob + 0]))
                   | ((uint_t)f2bf(relu_f(acc0[4 * g + 1] + eb2[e * 128 + ob + 1])) << 16);
        uint_t p01 = (uint_t)f2bf(relu_f(acc0[4 * g + 2] + eb2[e * 128 + ob + 2]))
                   | ((uint_t)f2bf(relu_f(acc0[4 * g + 3] + eb2[e * 128 + ob + 3])) << 16);
        uint_t p10 = (uint_t)f2bf(relu_f(acc1[4 * g + 0] + eb2[e * 128 + ob + 0]))
                   | ((uint_t)f2bf(relu_f(acc1[4 * g + 1] + eb2[e * 128 + ob + 1])) << 16);
        uint_t p11 = (uint_t)f2bf(relu_f(acc1[4 * g + 2] + eb2[e * 128 + ob + 2]))
                   | ((uint_t)f2bf(relu_f(acc1[4 * g + 3] + eb2[e * 128 + ob + 3])) << 16);
        uint2 v0; v0.x = p00; v0.y = p01;
        uint2 v1; v1.x = p10; v1.y = p11;
        *(uint2*)&oT[n][ob]      = v0;
        *(uint2*)&oT[32 + n][ob] = v1;
    }
    __syncthreads();
    ushort_t* E2k = E2u + (size_t)k * E2U_K_STRIDE;
    for (int i = t; i < 64 * 16; i += 256) {   // 16B chunks: 64 rows x 128 ushorts
        int qq = i >> 4, c8 = (i & 15) * 8;
        int q = q0 + qq;
        if (q < L2LEN)
            *(uint4*)(E2k + ((size_t)b * L2LEN + q) * 128 + c8) = *(const uint4*)&oT[qq][c8];
    }
}

// ---------------- expert conv3 (MFMA, both k in-block) + fused adaptive max-pool ----------------
// grid (9, 128). smem: xT [66][132] ushort (17424B) unioned with fT [128][66] float (33792B)
__global__ __launch_bounds__(256) void e3_kernel(const ushort_t* __restrict__ E2u,
                                                 const ushort_t* __restrict__ EW3P, const float* __restrict__ eb3,
                                                 const int* __restrict__ TI, const float* __restrict__ TW,
                                                 float* __restrict__ out) {
    __shared__ __align__(16) char smem[33792];
    ushort_t (*xT)[132] = (ushort_t (*)[132])smem;   // [66][132]
    float (*fT)[66] = (float (*)[66])smem;           // [128][66] (pad 66 breaks bank aliasing)
    int b = blockIdx.y;
    int q0 = blockIdx.x * 64;
    int t = threadIdx.x;
    int lane = t & 63;
    int w = rfl_i(t >> 6);
    int n = lane & 31;
    int kg = lane >> 5;
    float res0[16], res1[16];
    #pragma unroll
    for (int i = 0; i < 16; ++i) { res0[i] = 0.0f; res1[i] = 0.0f; }
    for (int k = 0; k < 2; ++k) {
        int e = rfl_i(TI[b * 2 + k]);
        float wk = rfl_f(TW[b * 2 + k]);
        const ushort_t* E2k = E2u + (size_t)k * E2U_K_STRIDE;
        __syncthreads();   // previous pass's xT reads done
        for (int i = t; i < 66 * 32; i += 256) {        // uint2 chunks: 66 rows x 128 ushorts
            int row = i >> 5, c4 = (i & 31) * 4;
            int pos = q0 - 1 + row;
            uint2 v; v.x = 0u; v.y = 0u;
            if (pos >= 0 && pos < L2LEN)
                v = *(const uint2*)(E2k + ((size_t)b * L2LEN + pos) * 128 + c4);
            *(uint2*)&xT[row][c4] = v;
        }
        __syncthreads();
        v16f acc0, acc1;
        #pragma unroll
        for (int i = 0; i < 16; ++i) { acc0[i] = 0.0f; acc1[i] = 0.0f; }
        #pragma unroll
        for (int t3 = 0; t3 < 3; ++t3) {
            const ushort_t* wrow = EW3P + (((e * 3 + t3) * 128) + w * 32 + n) * 128;
            #pragma unroll
            for (int ks = 0; ks < 8; ++ks) {
                int c0 = ks * 16 + kg * 8;
                v8s a = *(const v8s*)(wrow + c0);
                union { uint2 u[2]; v8s v; } b0u, b1u;
                const uint2* p0 = (const uint2*)&xT[n + t3][c0];
                const uint2* p1 = (const uint2*)&xT[n + 32 + t3][c0];
                b0u.u[0] = p0[0]; b0u.u[1] = p0[1];
                b1u.u[0] = p1[0]; b1u.u[1] = p1[1];
                acc0 = __builtin_amdgcn_mfma_f32_32x32x16_bf16(a, b0u.v, acc0, 0, 0, 0);
                acc1 = __builtin_amdgcn_mfma_f32_32x32x16_bf16(a, b1u.v, acc1, 0, 0, 0);
            }
        }
        #pragma unroll
        for (int r = 0; r < 16; ++r) {
            int m = (r & 3) + 8 * (r >> 2) + 4 * kg;
            float bias = eb3[e * 128 + w * 32 + m];
            res0[r] += relu_f(acc0[r] + bias) * wk;
            res1[r] += relu_f(acc1[r] + bias) * wk;
        }
    }
    __syncthreads();   // xT fully dead; smem becomes fT
    #pragma unroll
    for (int r = 0; r < 16; ++r) {
        int m = (r & 3) + 8 * (r >> 2) + 4 * kg;
        int o = w * 32 + m;
        fT[o][n]      = (q0 + n      < L2LEN) ? res0[r] : 0.0f;
        fT[o][32 + n] = (q0 + 32 + n < L2LEN) ? res1[r] : 0.0f;
    }
    __syncthreads();
    // adaptive max-pool: outputs j with window [s,e) intersecting [q0, qvend)
    int qvend = min(q0 + 64, L2LEN);
    int j_lo = (q0 * 256) / 513;
    while (j_lo > 0 && ((513 * j_lo + 255 + 513) >> 8) > q0) --j_lo;
    while (((513 * (j_lo + 1) + 255) >> 8) <= q0) ++j_lo;
    int j_hi = min(255, ((qvend * 256) / 513) + 1);
    while (((513 * j_hi) >> 8) >= qvend) --j_hi;
    int oo = t >> 1;
    for (int j = j_lo + (t & 1); j <= j_hi; j += 2) {
        int s = (513 * j) >> 8;
        int e_ = (513 * (j + 1) + 255) >> 8;
        int lo = max(s, q0), hi = min(e_, qvend);
        float m = fT[oo][lo - q0];
        for (int p = lo + 1; p < hi; ++p) m = fmaxf(m, fT[oo][p - q0]);
        int idx = (b * 128 + oo) * 256 + j;
        if (s >= q0 && e_ <= qvend) out[idx] = m;                          // interior: sole writer
        else atomicMax((int*)out + idx, __float_as_int(m));                // straddler: values >= 0
    }
}

extern "C" void kernel_launch(void* const* d_in, const int* in_sizes, int n_in,
                              void* d_out, int out_size, void* d_ws, size_t ws_size,
                              hipStream_t stream) {
    const float* x    = (const float*)d_in[0];
    const float* g_w1 = (const float*)d_in[1];
    const float* g_b1 = (const float*)d_in[2];
    const float* g_w2 = (const float*)d_in[3];
    const float* g_b2 = (const float*)d_in[4];
    const float* m_w1 = (const float*)d_in[5];
    const float* m_b1 = (const float*)d_in[6];
    const float* m_w2 = (const float*)d_in[7];
    const float* m_b2 = (const float*)d_in[8];
    const float* ew1  = (const float*)d_in[9];
    const float* eb1  = (const float*)d_in[10];
    const float* ew2  = (const float*)d_in[11];
    const float* eb2  = (const float*)d_in[12];
    const float* ew3  = (const float*)d_in[13];
    const float* eb3  = (const float*)d_in[14];

    float* ws     = (float*)d_ws;
    float* FFT    = ws + OFF_FFT;
    float* TWID   = ws + OFF_TWID;
    float* PTW    = ws + OFF_PTW;
    float* WIN    = ws + OFF_WIN;
    float* PART   = ws + OFF_PART;
    float* TW     = ws + OFF_TW;
    int*   TI     = (int*)(ws + OFF_TI);
    float* SRWLOG = ws + OFF_SRWLOG;
    ushort_t* W2H = (ushort_t*)(ws + OFF_W2H);
    ushort_t* W2L = (ushort_t*)(ws + OFF_W2L);
    ushort_t* EW2P = (ushort_t*)(ws + OFF_EW2P);
    ushort_t* EW3P = (ushort_t*)(ws + OFF_EW3P);
    uint_t* H1P   = (uint_t*)(ws + OFF_A);       // dead after g2
    ushort_t* E1u = (ushort_t*)(ws + OFF_A);     // overlays H1P (e1 runs after g2/mlp)
    ushort_t* E2u = (ushort_t*)(ws + OFF_E2U);
    float* out    = (float*)d_out;

    init_kernel<<<512, 256, 0, stream>>>(SRWLOG, TWID, PTW, WIN, W2H, W2L, EW2P, EW3P, out, g_w2, ew2, ew3);
    fft_kernel<<<128, 256, 0, stream>>>(x, TWID, PTW, WIN, FFT);
    g1_kernel<<<dim3(9, 128), 256, 0, stream>>>(FFT, g_w1, g_b1, H1P);
    g2_kernel<<<dim3(33, 128), 256, 0, stream>>>(H1P, W2H, W2L, g_b2, PART);
    mlp_kernel<<<128, 128, 0, stream>>>(PART, m_w1, m_b1, m_w2, m_b2, TW, TI, SRWLOG);
    aux_kernel<<<1, 64, 0, stream>>>(SRWLOG, out + 4194304);
    e1_kernel<<<dim3(5, 128, 2), 256, 0, stream>>>(FFT, ew1, eb1, TI, E1u);
    e2_kernel<<<dim3(9, 128, 2), 256, 0, stream>>>(E1u, EW2P, eb2, TI, E2u);
    e3_kernel<<<dim3(9, 128), 256, 0, stream>>>(E2u, EW3P, eb3, TI, TW, out);
}

// Round 8
// 289.397 us; speedup vs baseline: 3.3904x; 1.1364x over previous
//
#include <hip/hip_runtime.h>

#define NFREQ 2049
#define L1LEN 1025
#define L1STRIDE 1026
#define L2LEN 513

typedef short v8s  __attribute__((ext_vector_type(8)));
typedef float v16f __attribute__((ext_vector_type(16)));
typedef unsigned short ushort_t;
typedef unsigned int uint_t;

// ---------------- workspace layout (float offsets) ----------------
#define OFF_FFT     0ull          // 524544
#define OFF_TWID    524544ull     // 2048
#define OFF_PTW     526592ull     // 4352
#define OFF_WIN     530944ull     // 4096
#define OFF_PART    535040ull     // 540672
#define OFF_TW      1075712ull    // 256
#define OFF_TI      1075968ull    // 256 (ints)
#define OFF_SRWLOG  1076224ull    // 256
#define OFF_W2HF    1076480ull    // 5120  (ushort 10240, fragment-packed)
#define OFF_W2LF    1081600ull    // 5120
#define OFF_W2F     1086720ull    // 163840 (ushort 327680, fragment-packed)
#define OFF_W3F     1250560ull    // 196608 (ushort 393216, fragment-packed)
#define OFF_A       1447168ull    // H1P (uint 8392704) overlaid by E1u[2] (ushort 2*8404992)
#define OFF_E2U     9852160ull    // E2u[2] (ushort 2*8404992), layout [b][q][c]
// total 18,257,152 floats ~ 69.6 MiB

#define E1U_K_STRIDE 8404992      // ushort elements per k (128*64*1026)
#define E2U_K_STRIDE 8404992      // ushort elements per k (128*513*128)

__device__ __forceinline__ float relu_f(float x) { return fmaxf(x, 0.0f); }
__device__ __forceinline__ int   rfl_i(int v)   { return __builtin_amdgcn_readfirstlane(v); }
__device__ __forceinline__ float rfl_f(float v) { return __uint_as_float((unsigned)__builtin_amdgcn_readfirstlane((int)__float_as_uint(v))); }
__device__ __forceinline__ ushort_t f2bf(float x) {
    unsigned u = __float_as_uint(x);
    unsigned r = (u + 0x7FFFu + ((u >> 16) & 1u)) >> 16;   // RNE
    return (ushort_t)r;
}
__device__ __forceinline__ float bf2f(ushort_t h) { return __uint_as_float(((unsigned)h) << 16); }

// ---------------- init: tables + zero aux/out + fragment-pack weights ----------------
// Fragment order: for each MFMA instruction, 64 lanes read base + lane*16B.
// lane -> element: o = w*32 + (lane&31); c = ks*16 + (lane>>5)*8 + j  (j=0..7)
__global__ void init_kernel(float* SRWLOG, float* TWID, float* PTW, float* WIN,
                            ushort_t* W2HF, ushort_t* W2LF, ushort_t* W2F, ushort_t* W3F,
                            float* out0,
                            const float* g_w2, const float* ew2, const float* ew3) {
    const float PI = 3.14159265358979323846f;
    int tid = blockIdx.x * blockDim.x + threadIdx.x;
    int stride = gridDim.x * blockDim.x;
    for (int i = tid; i < 16; i += stride) SRWLOG[i] = 0.0f;
    for (int i = tid; i < 4194304; i += stride) out0[i] = 0.0f;   // maxpool accum base (values >= 0)
    for (int j = tid; j < 1024; j += stride) {
        float a = PI * (float)j / 1024.0f;
        TWID[2 * j] = cosf(a);
        TWID[2 * j + 1] = -sinf(a);
    }
    for (int k = tid; k < 2049; k += stride) {
        float a = PI * (float)k / 2048.0f;
        PTW[2 * k] = cosf(a);
        PTW[2 * k + 1] = sinf(a);
    }
    for (int n = tid; n < 4096; n += stride) {
        WIN[n] = 0.5f * (1.0f - cosf(2.0f * PI * (float)n / 4096.0f));
    }
    // g_w2 (64,32,5) -> W2HF/W2LF frag id=((t5*2+tile)*2+ks)
    for (int i = tid; i < 10240; i += stride) {
        int j = i & 7;
        int lane = (i >> 3) & 63;
        int ks = (i >> 9) & 1;
        int tile = (i >> 10) & 1;
        int t = i >> 11;                       // 0..4
        int o = tile * 32 + (lane & 31);
        int c = ks * 16 + (lane >> 5) * 8 + j;
        float w = g_w2[o * 160 + c * 5 + t];
        ushort_t h = f2bf(w);
        W2HF[i] = h;
        W2LF[i] = f2bf(w - bf2f(h));
    }
    // ew2 (8,128,64,5) -> W2F frag id=(((e*5+t5)*4+w)*4+ks)
    for (int i = tid; i < 327680; i += stride) {
        int j = i & 7;
        int lane = (i >> 3) & 63;
        int ks = (i >> 9) & 3;
        int w = (i >> 11) & 3;
        int t = (i >> 13) % 5;
        int e = i / 40960;
        int o = w * 32 + (lane & 31);
        int c = ks * 16 + (lane >> 5) * 8 + j;
        W2F[i] = f2bf(ew2[((e * 128 + o) * 64 + c) * 5 + t]);
    }
    // ew3 (8,128,128,3) -> W3F frag id=(((e*3+t3)*4+w)*8+ks)
    for (int i = tid; i < 393216; i += stride) {
        int j = i & 7;
        int lane = (i >> 3) & 63;
        int ks = (i >> 9) & 7;
        int w = (i >> 12) & 3;
        int t = (i >> 14) % 3;
        int e = i / 49152;
        int o = w * 32 + (lane & 31);
        int c = ks * 16 + (lane >> 5) * 8 + j;
        W3F[i] = f2bf(ew3[((e * 128 + o) * 128 + c) * 3 + t]);
    }
}

// ---------------- windowed rfft(4096) via 2048-pt complex FFT (table-driven) ----------------
__global__ __launch_bounds__(256) void fft_kernel(const float* __restrict__ x,
                                                  const float* __restrict__ TWID,
                                                  const float* __restrict__ PTW,
                                                  const float* __restrict__ WIN,
                                                  float* __restrict__ FFT) {
    __shared__ float re[2048];
    __shared__ float im[2048];
    int b = blockIdx.x, t = threadIdx.x;
    const float* xb = x + b * 4096;
    for (int i = t; i < 2048; i += 256) {
        int j = (int)(__brev((unsigned)i) >> 21);   // 11-bit reversal
        re[i] = xb[2 * j] * WIN[2 * j];
        im[i] = xb[2 * j + 1] * WIN[2 * j + 1];
    }
    for (int s = 1; s <= 11; ++s) {
        __syncthreads();
        int half = 1 << (s - 1);
        int shift = 11 - s;
        for (int bf = t; bf < 1024; bf += 256) {
            int grp = bf >> (s - 1);
            int pos = bf & (half - 1);
            int i1 = (grp << s) + pos;
            int i2 = i1 + half;
            int j = pos << shift;
            float wr = TWID[2 * j], wi = TWID[2 * j + 1];
            float ar = re[i2], ai = im[i2];
            float tr = wr * ar - wi * ai;
            float ti = wr * ai + wi * ar;
            float br = re[i1], bi = im[i1];
            re[i2] = br - tr; im[i2] = bi - ti;
            re[i1] = br + tr; im[i1] = bi + ti;
        }
    }
    __syncthreads();
    const float scale = 1.0f / 64.0f;
    for (int k = t; k <= 2048; k += 256) {
        int k1 = k & 2047;
        int k2 = (2048 - k) & 2047;
        float zr = re[k1], zi = im[k1];
        float yr = re[k2], yi = im[k2];
        float Er = 0.5f * (zr + yr), Ei = 0.5f * (zi - yi);
        float Or = 0.5f * (zi + yi), Oi = 0.5f * (yr - zr);
        float c2 = PTW[2 * k], s3 = PTW[2 * k + 1];
        FFT[b * 4098 + k]        = (Er + c2 * Or + s3 * Oi) * scale;
        FFT[b * 4098 + 2049 + k] = (Ei + c2 * Oi - s3 * Or) * scale;
    }
}

// ---------------- gate conv1 -> H1P packed (hi|lo) bf16, layout [b][pos][c] ----------------
__global__ __launch_bounds__(256) void g1_kernel(const float* __restrict__ FFT,
                                                 const float* __restrict__ g_w1, const float* __restrict__ g_b1,
                                                 uint_t* __restrict__ H1P) {
    int pos = blockIdx.x * 256 + threadIdx.x;
    if (pos >= NFREQ) return;
    int b = blockIdx.y;
    const float* fb = FFT + b * 4098;
    float f[2][5];
    #pragma unroll
    for (int cc = 0; cc < 2; ++cc)
        #pragma unroll
        for (int tt = 0; tt < 5; ++tt) {
            int p = pos - 2 + tt;
            f[cc][tt] = (p >= 0 && p < NFREQ) ? fb[cc * NFREQ + p] : 0.0f;
        }
    uint_t* outp = H1P + (b * NFREQ + pos) * 32;
    #pragma unroll
    for (int o = 0; o < 32; ++o) {
        float a = g_b1[o];
        #pragma unroll
        for (int cc = 0; cc < 2; ++cc)
            #pragma unroll
            for (int tt = 0; tt < 5; ++tt)
                a = fmaf(f[cc][tt], g_w1[(o * 2 + cc) * 5 + tt], a);
        a = relu_f(a);
        ushort_t h = f2bf(a);
        ushort_t l = f2bf(a - bf2f(h));
        outp[o] = (uint_t)h | ((uint_t)l << 16);
    }
}

// ---------------- gate conv2 (split-precision MFMA) + partial mean-pool ----------------
__global__ __launch_bounds__(256) void g2_kernel(const uint_t* __restrict__ H1P,
                                                 const ushort_t* __restrict__ W2HF, const ushort_t* __restrict__ W2LF,
                                                 const float* __restrict__ g_b2,
                                                 float* __restrict__ PART) {
    __shared__ ushort_t xh[68][36];
    __shared__ ushort_t xl[68][36];
    int b = blockIdx.y;
    int q0 = blockIdx.x * 64;
    int t = threadIdx.x;
    for (int i = t; i < 68 * 32; i += 256) {
        int row = i >> 5, c = i & 31;
        int pos = q0 - 2 + row;
        uint_t v = (pos >= 0 && pos < NFREQ) ? H1P[(b * NFREQ + pos) * 32 + c] : 0u;
        xh[row][c] = (ushort_t)(v & 0xFFFFu);
        xl[row][c] = (ushort_t)(v >> 16);
    }
    __syncthreads();
    int lane = t & 63;
    int w = rfl_i(t >> 6);
    int tile = w & 1;
    int qh = w >> 1;
    int n = lane & 31;
    int kg = lane >> 5;
    v16f acc;
    #pragma unroll
    for (int i = 0; i < 16; ++i) acc[i] = 0.0f;
    #pragma unroll
    for (int t5 = 0; t5 < 5; ++t5) {
        int row = qh * 32 + n + t5;
        #pragma unroll
        for (int ks = 0; ks < 2; ++ks) {
            int c0 = ks * 16 + kg * 8;
            v8s Ah = *(const v8s*)(W2HF + (((t5 * 2 + tile) * 2 + ks) << 9) + lane * 8);
            v8s Al = *(const v8s*)(W2LF + (((t5 * 2 + tile) * 2 + ks) << 9) + lane * 8);
            union { uint2 u[2]; v8s v; } Bh, Bl;
            const uint2* ph = (const uint2*)&xh[row][c0];
            const uint2* pl = (const uint2*)&xl[row][c0];
            Bh.u[0] = ph[0]; Bh.u[1] = ph[1];
            Bl.u[0] = pl[0]; Bl.u[1] = pl[1];
            acc = __builtin_amdgcn_mfma_f32_32x32x16_bf16(Ah, Bh.v, acc, 0, 0, 0);
            acc = __builtin_amdgcn_mfma_f32_32x32x16_bf16(Ah, Bl.v, acc, 0, 0, 0);
            acc = __builtin_amdgcn_mfma_f32_32x32x16_bf16(Al, Bh.v, acc, 0, 0, 0);
        }
    }
    int q = q0 + qh * 32 + n;
    bool valid = (q < NFREQ);
    #pragma unroll
    for (int r = 0; r < 16; ++r) {
        int m = (r & 3) + 8 * (r >> 2) + 4 * kg;
        int o = tile * 32 + m;
        float v = valid ? relu_f(acc[r] + g_b2[o]) : 0.0f;
        #pragma unroll
        for (int msk = 16; msk >= 1; msk >>= 1) v += __shfl_xor(v, msk, 64);
        if (n == 0) PART[(b * 64 + o) * 66 + blockIdx.x * 2 + qh] = v;
    }
}

// ---------------- router MLP + softmax + top2 + aux partials ----------------
__global__ __launch_bounds__(128) void mlp_kernel(const float* __restrict__ PART,
                                                  const float* __restrict__ m_w1, const float* __restrict__ m_b1,
                                                  const float* __restrict__ m_w2, const float* __restrict__ m_b2,
                                                  float* TW, int* TI, float* SRWLOG) {
    __shared__ float pooledS[64];
    __shared__ float hid[128];
    __shared__ float lgS[8];
    __shared__ float rwS[8];
    int b = blockIdx.x, t = threadIdx.x;
    if (t < 64) {
        float s = 0.0f;
        const float* pp = PART + (b * 64 + t) * 66;
        for (int blk = 0; blk < 66; ++blk) s += pp[blk];
        pooledS[t] = s;
    }
    __syncthreads();
    const float inv = 1.0f / 2049.0f;
    {
        float h = m_b1[t];
        for (int c = 0; c < 64; ++c)
            h = fmaf(pooledS[c] * inv, m_w1[t * 64 + c], h);
        hid[t] = relu_f(h);
    }
    __syncthreads();
    if (t < 8) {
        float lg = m_b2[t];
        for (int j = 0; j < 128; ++j) lg = fmaf(hid[j], m_w2[t * 128 + j], lg);
        lgS[t] = lg;
    }
    __syncthreads();
    if (t == 0) {
        float mx = lgS[0];
        for (int e = 1; e < 8; ++e) mx = fmaxf(mx, lgS[e]);
        float s = 0.0f, ex[8];
        for (int e = 0; e < 8; ++e) { ex[e] = expf(lgS[e] - mx); s += ex[e]; }
        for (int e = 0; e < 8; ++e) rwS[e] = ex[e] / s;
        int i1 = 0;
        for (int e = 1; e < 8; ++e) if (rwS[e] > rwS[i1]) i1 = e;
        int i2 = (i1 == 0) ? 1 : 0;
        for (int e = 0; e < 8; ++e) if (e != i1 && rwS[e] > rwS[i2]) i2 = e;
        float t0 = rwS[i1], t1 = rwS[i2], sm = t0 + t1;
        TW[b * 2] = t0 / sm; TW[b * 2 + 1] = t1 / sm;
        TI[b * 2] = i1; TI[b * 2 + 1] = i2;
    }
    __syncthreads();
    if (t < 8) {
        atomicAdd(&SRWLOG[t], rwS[t]);
        atomicAdd(&SRWLOG[8 + t], lgS[t]);
    }
}

__global__ void aux_kernel(const float* SRWLOG, float* out_aux) {
    if (threadIdx.x == 0 && blockIdx.x == 0) {
        float a = 0.0f;
        for (int e = 0; e < 8; ++e)
            a += (SRWLOG[e] / 128.0f) * (SRWLOG[8 + e] / 128.0f);
        out_aux[0] = 0.01f * 8.0f * a;
    }
}

// ---------------- expert conv1: (2->64, k=7, s=2, p=3), bf16 out, row stride 1026 ----------------
__global__ __launch_bounds__(256) void e1_kernel(const float* __restrict__ FFT,
                                                 const float* __restrict__ ew1, const float* __restrict__ eb1,
                                                 const int* __restrict__ TI, ushort_t* __restrict__ E1u) {
    __shared__ float xs[2][520];
    int r0 = blockIdx.x * 256;
    int b = blockIdx.y;
    int k = blockIdx.z;
    int t = threadIdx.x;
    int e = rfl_i(TI[b * 2 + k]);
    int lo = 2 * r0 - 3;
    const float* fb = FFT + b * 4098;
    for (int i = t; i < 2 * 520; i += 256) {
        int ch = i / 520, off = i % 520;
        int pos = lo + off;
        xs[ch][off] = (pos >= 0 && pos < NFREQ) ? fb[ch * NFREQ + pos] : 0.0f;
    }
    __syncthreads();
    int r = r0 + t;
    if (r >= L1LEN) return;
    float xv[14];
    #pragma unroll
    for (int ch = 0; ch < 2; ++ch)
        #pragma unroll
        for (int tt = 0; tt < 7; ++tt)
            xv[ch * 7 + tt] = xs[ch][2 * t + tt];
    const float* wb = ew1 + e * 64 * 14;
    const float* bb = eb1 + e * 64;
    ushort_t* outb = E1u + (size_t)k * E1U_K_STRIDE + (size_t)b * 64 * L1STRIDE + r;
    bool last = (r == L1LEN - 1);
    for (int o = 0; o < 64; ++o) {
        float a = bb[o];
        const float* w = wb + o * 14;
        #pragma unroll
        for (int j = 0; j < 14; ++j)
            a = fmaf(xv[j], w[j], a);
        outb[o * L1STRIDE] = f2bf(relu_f(a));
        if (last) outb[o * L1STRIDE + 1] = 0;   // zero pad slot 1025 for e2's uint loads
    }
}

// ---------------- expert conv2 (MFMA): (64->128, k=5, s=2, p=2) -> E2 [b][q][c] ----------------
// grid (128, 9, 2): b-fastest so same-b neighbors colocate on an XCD
__global__ __launch_bounds__(256) void e2_kernel(const ushort_t* __restrict__ E1u,
                                                 const ushort_t* __restrict__ W2F, const float* __restrict__ eb2,
                                                 const int* __restrict__ TI, ushort_t* __restrict__ E2u) {
    __shared__ __align__(16) char sm2[17952];
    ushort_t (*xe)[68] = (ushort_t (*)[68])sm2;            // [66][68]
    ushort_t (*xo)[68] = (ushort_t (*)[68])(sm2 + 8976);   // [66][68]
    ushort_t (*oT)[136] = (ushort_t (*)[136])sm2;          // [64][136] (reuses sm2 after MFMA)
    int b = blockIdx.x;
    int k = blockIdx.z;
    int q0 = blockIdx.y * 64;
    int t = threadIdx.x;
    int e = rfl_i(TI[b * 2 + k]);
    const ushort_t* E1k = E1u + (size_t)k * E1U_K_STRIDE;
    for (int i = t; i < 64 * 66; i += 256) {
        int c = i / 66, j = i % 66;
        int p = 2 * q0 - 2 + 2 * j;          // even position; pair (p, p+1)
        uint_t v = 0;
        if (p >= 0 && p < L1LEN)             // p==1024 ok: slot 1025 is zeroed pad
            v = *(const uint_t*)(E1k + (size_t)(b * 64 + c) * L1STRIDE + p);
        xe[j][c] = (ushort_t)(v & 0xFFFFu);
        xo[j][c] = (ushort_t)(v >> 16);
    }
    __syncthreads();
    int lane = t & 63;
    int w = rfl_i(t >> 6);
    int n = lane & 31;
    int kg = lane >> 5;
    v16f acc0, acc1;
    #pragma unroll
    for (int i = 0; i < 16; ++i) { acc0[i] = 0.0f; acc1[i] = 0.0f; }
    #pragma unroll
    for (int t5 = 0; t5 < 5; ++t5) {
        int roff = t5 >> 1;
        const ushort_t (*sel)[68] = (t5 & 1) ? xo : xe;
        const ushort_t* wfrag = W2F + ((((e * 5 + t5) * 4 + w) * 4) << 9) + lane * 8;
        #pragma unroll
        for (int ks = 0; ks < 4; ++ks) {
            int c0 = ks * 16 + kg * 8;
            v8s a = *(const v8s*)(wfrag + (ks << 9));
            union { uint2 u[2]; v8s v; } b0u, b1u;
            const uint2* p0 = (const uint2*)&sel[n + roff][c0];
            const uint2* p1 = (const uint2*)&sel[n + 32 + roff][c0];
            b0u.u[0] = p0[0]; b0u.u[1] = p0[1];
            b1u.u[0] = p1[0]; b1u.u[1] = p1[1];
            acc0 = __builtin_amdgcn_mfma_f32_32x32x16_bf16(a, b0u.v, acc0, 0, 0, 0);
            acc1 = __builtin_amdgcn_mfma_f32_32x32x16_bf16(a, b1u.v, acc1, 0, 0, 0);
        }
    }
    __syncthreads();   // xe/xo dead -> oT
    #pragma unroll
    for (int g = 0; g < 4; ++g) {
        int ob = w * 32 + 8 * g + 4 * kg;    // 4 consecutive o per C-frag quad
        uint_t p00 = (uint_t)f2bf(relu_f(acc0[4 * g + 0] + eb2[e * 128 + ob + 0]))
                   | ((uint_t)f2bf(relu_f(acc0[4 * g + 1] + eb2[e * 128 + ob + 1])) << 16);
        uint_t p01 = (uint_t)f2bf(relu_f(acc0[4 * g + 2] + eb2[e * 128 + ob + 2]))
                   | ((uint_t)f2bf(relu_f(acc0[4 * g + 3] + eb2[e * 128 + ob + 3])) << 16);
        uint_t p10 = (uint_t)f2bf(relu_f(acc1[4 * g + 0] + eb2[e * 128 + ob + 0]))
                   | ((uint_t)f2bf(relu_f(acc1[4 * g + 1] + eb2[e * 128 + ob + 1])) << 16);
        uint_t p11 = (uint_t)f2bf(relu_f(acc1[4 * g + 2] + eb2[e * 128 + ob + 2]))
                   | ((uint_t)f2bf(relu_f(acc1[4 * g + 3] + eb2[e * 128 + ob + 3])) << 16);
        uint2 v0; v0.x = p00; v0.y = p01;
        uint2 v1; v1.x = p10; v1.y = p11;
        *(uint2*)&oT[n][ob]      = v0;
        *(uint2*)&oT[32 + n][ob] = v1;
    }
    __syncthreads();
    ushort_t* E2k = E2u + (size_t)k * E2U_K_STRIDE;
    for (int i = t; i < 64 * 16; i += 256) {   // 16B chunks: 64 rows x 128 ushorts
        int qq = i >> 4, c8 = (i & 15) * 8;
        int q = q0 + qq;
        if (q < L2LEN)
            *(uint4*)(E2k + ((size_t)b * L2LEN + q) * 128 + c8) = *(const uint4*)&oT[qq][c8];
    }
}

// ---------------- expert conv3 (MFMA, both k in-block) + fused adaptive max-pool ----------------
// grid (128, 9): b-fastest. smem: xT [66][132] ushort unioned with fT [128][66] float
__global__ __launch_bounds__(256) void e3_kernel(const ushort_t* __restrict__ E2u,
                                                 const ushort_t* __restrict__ W3F, const float* __restrict__ eb3,
                                                 const int* __restrict__ TI, const float* __restrict__ TW,
                                                 float* __restrict__ out) {
    __shared__ __align__(16) char smem[33792];
    ushort_t (*xT)[132] = (ushort_t (*)[132])smem;   // [66][132]
    float (*fT)[66] = (float (*)[66])smem;           // [128][66] (pad 66 breaks bank aliasing)
    int b = blockIdx.x;
    int q0 = blockIdx.y * 64;
    int t = threadIdx.x;
    int lane = t & 63;
    int w = rfl_i(t >> 6);
    int n = lane & 31;
    int kg = lane >> 5;
    float res0[16], res1[16];
    #pragma unroll
    for (int i = 0; i < 16; ++i) { res0[i] = 0.0f; res1[i] = 0.0f; }
    for (int k = 0; k < 2; ++k) {
        int e = rfl_i(TI[b * 2 + k]);
        float wk = rfl_f(TW[b * 2 + k]);
        const ushort_t* E2k = E2u + (size_t)k * E2U_K_STRIDE;
        __syncthreads();   // previous pass's xT reads done
        for (int i = t; i < 66 * 32; i += 256) {        // uint2 chunks: 66 rows x 128 ushorts
            int row = i >> 5, c4 = (i & 31) * 4;
            int pos = q0 - 1 + row;
            uint2 v; v.x = 0u; v.y = 0u;
            if (pos >= 0 && pos < L2LEN)
                v = *(const uint2*)(E2k + ((size_t)b * L2LEN + pos) * 128 + c4);
            *(uint2*)&xT[row][c4] = v;
        }
        __syncthreads();
        v16f acc0, acc1;
        #pragma unroll
        for (int i = 0; i < 16; ++i) { acc0[i] = 0.0f; acc1[i] = 0.0f; }
        #pragma unroll
        for (int t3 = 0; t3 < 3; ++t3) {
            const ushort_t* wfrag = W3F + ((((e * 3 + t3) * 4 + w) * 8) << 9) + lane * 8;
            #pragma unroll
            for (int ks = 0; ks < 8; ++ks) {
                int c0 = ks * 16 + kg * 8;
                v8s a = *(const v8s*)(wfrag + (ks << 9));
                union { uint2 u[2]; v8s v; } b0u, b1u;
                const uint2* p0 = (const uint2*)&xT[n + t3][c0];
                const uint2* p1 = (const uint2*)&xT[n + 32 + t3][c0];
                b0u.u[0] = p0[0]; b0u.u[1] = p0[1];
                b1u.u[0] = p1[0]; b1u.u[1] = p1[1];
                acc0 = __builtin_amdgcn_mfma_f32_32x32x16_bf16(a, b0u.v, acc0, 0, 0, 0);
                acc1 = __builtin_amdgcn_mfma_f32_32x32x16_bf16(a, b1u.v, acc1, 0, 0, 0);
            }
        }
        #pragma unroll
        for (int r = 0; r < 16; ++r) {
            int m = (r & 3) + 8 * (r >> 2) + 4 * kg;
            float bias = eb3[e * 128 + w * 32 + m];
            res0[r] += relu_f(acc0[r] + bias) * wk;
            res1[r] += relu_f(acc1[r] + bias) * wk;
        }
    }
    __syncthreads();   // xT fully dead; smem becomes fT
    #pragma unroll
    for (int r = 0; r < 16; ++r) {
        int m = (r & 3) + 8 * (r >> 2) + 4 * kg;
        int o = w * 32 + m;
        fT[o][n]      = (q0 + n      < L2LEN) ? res0[r] : 0.0f;
        fT[o][32 + n] = (q0 + 32 + n < L2LEN) ? res1[r] : 0.0f;
    }
    __syncthreads();
    // adaptive max-pool: outputs j whose window [s,e) intersects [q0, qvend)
    int qvend = min(q0 + 64, L2LEN);
    int j_lo = (256 * q0) / 513;
    while (((513 * (j_lo + 1) + 255) >> 8) <= q0) ++j_lo;   // advance until e(j_lo) > q0
    int j_hi = min(255, (256 * qvend) / 513);
    while (((513 * j_hi) >> 8) >= qvend) --j_hi;            // retreat until s(j_hi) < qvend
    int oo = t >> 1;
    for (int j = j_lo + (t & 1); j <= j_hi; j += 2) {
        int s = (513 * j) >> 8;
        int e_ = (513 * (j + 1) + 255) >> 8;
        int lo = max(s, q0), hi = min(e_, qvend);
        if (hi <= lo) continue;
        float m = fT[oo][lo - q0];
        for (int p = lo + 1; p < hi; ++p) m = fmaxf(m, fT[oo][p - q0]);
        int idx = (b * 128 + oo) * 256 + j;
        if (s >= q0 && e_ <= qvend) out[idx] = m;                          // interior: sole writer
        else atomicMax((int*)out + idx, __float_as_int(m));                // straddler: values >= 0
    }
}

extern "C" void kernel_launch(void* const* d_in, const int* in_sizes, int n_in,
                              void* d_out, int out_size, void* d_ws, size_t ws_size,
                              hipStream_t stream) {
    const float* x    = (const float*)d_in[0];
    const float* g_w1 = (const float*)d_in[1];
    const float* g_b1 = (const float*)d_in[2];
    const float* g_w2 = (const float*)d_in[3];
    const float* g_b2 = (const float*)d_in[4];
    const float* m_w1 = (const float*)d_in[5];
    const float* m_b1 = (const float*)d_in[6];
    const float* m_w2 = (const float*)d_in[7];
    const float* m_b2 = (const float*)d_in[8];
    const float* ew1  = (const float*)d_in[9];
    const float* eb1  = (const float*)d_in[10];
    const float* ew2  = (const float*)d_in[11];
    const float* eb2  = (const float*)d_in[12];
    const float* ew3  = (const float*)d_in[13];
    const float* eb3  = (const float*)d_in[14];

    float* ws     = (float*)d_ws;
    float* FFT    = ws + OFF_FFT;
    float* TWID   = ws + OFF_TWID;
    float* PTW    = ws + OFF_PTW;
    float* WIN    = ws + OFF_WIN;
    float* PART   = ws + OFF_PART;
    float* TW     = ws + OFF_TW;
    int*   TI     = (int*)(ws + OFF_TI);
    float* SRWLOG = ws + OFF_SRWLOG;
    ushort_t* W2HF = (ushort_t*)(ws + OFF_W2HF);
    ushort_t* W2LF = (ushort_t*)(ws + OFF_W2LF);
    ushort_t* W2F  = (ushort_t*)(ws + OFF_W2F);
    ushort_t* W3F  = (ushort_t*)(ws + OFF_W3F);
    uint_t* H1P   = (uint_t*)(ws + OFF_A);       // dead after g2
    ushort_t* E1u = (ushort_t*)(ws + OFF_A);     // overlays H1P (e1 runs after g2/mlp)
    ushort_t* E2u = (ushort_t*)(ws + OFF_E2U);
    float* out    = (float*)d_out;

    init_kernel<<<512, 256, 0, stream>>>(SRWLOG, TWID, PTW, WIN, W2HF, W2LF, W2F, W3F, out, g_w2, ew2, ew3);
    fft_kernel<<<128, 256, 0, stream>>>(x, TWID, PTW, WIN, FFT);
    g1_kernel<<<dim3(9, 128), 256, 0, stream>>>(FFT, g_w1, g_b1, H1P);
    g2_kernel<<<dim3(33, 128), 256, 0, stream>>>(H1P, W2HF, W2LF, g_b2, PART);
    mlp_kernel<<<128, 128, 0, stream>>>(PART, m_w1, m_b1, m_w2, m_b2, TW, TI, SRWLOG);
    aux_kernel<<<1, 64, 0, stream>>>(SRWLOG, out + 4194304);
    e1_kernel<<<dim3(5, 128, 2), 256, 0, stream>>>(FFT, ew1, eb1, TI, E1u);
    e2_kernel<<<dim3(128, 9, 2), 256, 0, stream>>>(E1u, W2F, eb2, TI, E2u);
    e3_kernel<<<dim3(128, 9), 256, 0, stream>>>(E2u, W3F, eb3, TI, TW, out);
}